// Round 9
// baseline (337.774 us; speedup 1.0000x reference)
//
#include <hip/hip_runtime.h>
#include <hip/hip_bf16.h>
#include <math.h>

#define S_LEN 2048
#define D_MODEL 2048
#define Q_HEADS 32
#define KV_HEADS 8

typedef __attribute__((ext_vector_type(8))) short short8;   // 8 bf16 = 4 VGPRs
typedef __attribute__((ext_vector_type(4))) float f32x4;

// ---------------------------------------------------------------------------
// helpers
// ---------------------------------------------------------------------------
__device__ __forceinline__ short bf16_rne(float f) {
  unsigned u = __float_as_uint(f);
  unsigned r = (u + 0x7FFFu + ((u >> 16) & 1u)) >> 16;
  return (short)r;
}
// async global->LDS DMA, 16B per lane; lds dest = wave-uniform base + lane*16
__device__ __forceinline__ void dma16(const short* g, short* l) {
  __builtin_amdgcn_global_load_lds(
      (const __attribute__((address_space(1))) void*)g,
      (__attribute__((address_space(3))) void*)l, 16, 0, 0);
}
// hw trig on fp32 theta (radians) via fp64 range reduction to revolutions
__device__ __forceinline__ void fast_sincos(float theta, float& sn, float& cs) {
  double rev = (double)theta * 0.15915494309189535;  // theta / 2pi
  float fr = (float)(rev - floor(rev));
  sn = __builtin_amdgcn_sinf(fr);
  cs = __builtin_amdgcn_cosf(fr);
}
__device__ __forceinline__ void cvt8(const float* src, short* dst, int i) {
  float4 a = *(const float4*)&src[i];
  float4 b = *(const float4*)&src[i + 4];
  short8 h;
  h[0] = bf16_rne(a.x); h[1] = bf16_rne(a.y);
  h[2] = bf16_rne(a.z); h[3] = bf16_rne(a.w);
  h[4] = bf16_rne(b.x); h[5] = bf16_rne(b.y);
  h[6] = bf16_rne(b.z); h[7] = bf16_rne(b.w);
  *(short8*)&dst[i] = h;
}

// ---------------------------------------------------------------------------
// Fused fp32->bf16 conversion of x, W_q, W_kv, W_out in ONE launch.
// ---------------------------------------------------------------------------
#define NM (2048 * 2048)
#define NKV (1024 * 2048)

__global__ __launch_bounds__(256) void cvt_all(
    const float* __restrict__ x,    short* __restrict__ xh,
    const float* __restrict__ wq,   short* __restrict__ wqh,
    const float* __restrict__ wkv,  short* __restrict__ wkvh,
    const float* __restrict__ wo,   short* __restrict__ woh) {
  int i = (blockIdx.x * 256 + threadIdx.x) * 8;
  if (i < NM) { cvt8(x, xh, i); return; }
  i -= NM;
  if (i < NM) { cvt8(wq, wqh, i); return; }
  i -= NM;
  if (i < NKV) { cvt8(wkv, wkvh, i); return; }
  i -= NKV;
  cvt8(wo, woh, i);
}

// ---------------------------------------------------------------------------
// NT1 GEMM with dual output (Q | KV concat on the N axis), DMA staging,
// double-buffered (prefetch t+1 overlaps MFMA of t; barrier drains vmcnt).
// ---------------------------------------------------------------------------
__global__ __launch_bounds__(256) void gemm_nt1_dual(
    const short* __restrict__ Ah,
    const short* __restrict__ Bq, const short* __restrict__ Bkv,
    const float* __restrict__ bq, const float* __restrict__ bkv,
    float* __restrict__ Cq, float* __restrict__ Ckv,
    int Nq, int Nkv, int K) {
  __shared__ short As[2][128 * 32];
  __shared__ short Bs[2][128 * 32];
  const int tid = threadIdx.x;
  const int w = tid >> 6, lane = tid & 63;
  const int l16 = lane & 15, quad = lane >> 4;
  const int bm = blockIdx.y * 128;
  const int bnG = blockIdx.x * 128;

  const short* Bsrc; const float* bias; float* Cp; int pitch; int bn;
  if (bnG < Nq) { Bsrc = Bq;  bias = bq;  Cp = Cq;  pitch = Nq;  bn = bnG; }
  else          { Bsrc = Bkv; bias = bkv; Cp = Ckv; pitch = Nkv; bn = bnG - Nq; }

  const int drow0 = w * 16 + (lane >> 2);
  const int drow1 = drow0 + 64;
  const int slot = lane & 3;
  const int ch0 = slot ^ ((drow0 >> 1) & 3);
  const int ch1 = slot ^ ((drow1 >> 1) & 3);
  const short* gA0 = &Ah[(size_t)(bm + drow0) * K + ch0 * 8];
  const short* gA1 = &Ah[(size_t)(bm + drow1) * K + ch1 * 8];
  const short* gB0 = &Bsrc[(size_t)(bn + drow0) * K + ch0 * 8];
  const short* gB1 = &Bsrc[(size_t)(bn + drow1) * K + ch1 * 8];
  const int dA0 = (w * 16) * 32, dA1 = (64 + w * 16) * 32;

  const int wm = (w & 1) * 64, wn = (w >> 1) * 64;
  int offA[4], offB[4];
#pragma unroll
  for (int i = 0; i < 4; ++i) {
    int R = wm + i * 16 + l16;
    offA[i] = R * 32 + (quad ^ ((R >> 1) & 3)) * 8;
    int Rb = wn + i * 16 + l16;
    offB[i] = Rb * 32 + (quad ^ ((Rb >> 1) & 3)) * 8;
  }

  f32x4 acc[4][4];
#pragma unroll
  for (int i = 0; i < 4; ++i)
#pragma unroll
    for (int j = 0; j < 4; ++j)
#pragma unroll
      for (int e = 0; e < 4; ++e) acc[i][j][e] = 0.f;

  const int T = K / 32;
  dma16(gA0, &As[0][dA0]);
  dma16(gA1, &As[0][dA1]);
  dma16(gB0, &Bs[0][dA0]);
  dma16(gB1, &Bs[0][dA1]);
  __syncthreads();

  for (int t = 0; t < T; ++t) {
    const int cur = t & 1, nxt = cur ^ 1;
    if (t + 1 < T) {
      const int ko = (t + 1) * 32;
      dma16(gA0 + ko, &As[nxt][dA0]);
      dma16(gA1 + ko, &As[nxt][dA1]);
      dma16(gB0 + ko, &Bs[nxt][dA0]);
      dma16(gB1 + ko, &Bs[nxt][dA1]);
    }
    short8 af[4], bf[4];
#pragma unroll
    for (int i = 0; i < 4; ++i) af[i] = *(const short8*)&As[cur][offA[i]];
#pragma unroll
    for (int j = 0; j < 4; ++j) bf[j] = *(const short8*)&Bs[cur][offB[j]];
#pragma unroll
    for (int i = 0; i < 4; ++i)
#pragma unroll
      for (int j = 0; j < 4; ++j)
        acc[i][j] = __builtin_amdgcn_mfma_f32_16x16x32_bf16(af[i], bf[j], acc[i][j], 0, 0, 0);
    __syncthreads();   // reads of cur done; dma(t+1) drained
  }

#pragma unroll
  for (int i = 0; i < 4; ++i) {
#pragma unroll
    for (int j = 0; j < 4; ++j) {
      const int col = bn + wn + j * 16 + l16;
      const float bv = bias[col];
      const int row0 = bm + wm + i * 16 + quad * 4;
#pragma unroll
      for (int e = 0; e < 4; ++e)
        Cp[(size_t)(row0 + e) * pitch + col] = acc[i][j][e] + bv;
    }
  }
}

// ---------------------------------------------------------------------------
// Single-output bf16 NT GEMM, BM=BN=128 (out-projection). Same structure as
// the dual kernel; 32 MFMA : 16 LDS frag reads per k-step.
// ---------------------------------------------------------------------------
__global__ __launch_bounds__(256) void gemm_nt1_big(
    const short* __restrict__ A, const short* __restrict__ B,
    const float* __restrict__ bias, float* __restrict__ C,
    int N, int K) {
  __shared__ short As[2][128 * 32];
  __shared__ short Bs[2][128 * 32];
  const int tid = threadIdx.x;
  const int w = tid >> 6, lane = tid & 63;
  const int l16 = lane & 15, quad = lane >> 4;
  const int bm = blockIdx.y * 128;
  const int bn = blockIdx.x * 128;

  const int drow0 = w * 16 + (lane >> 2);
  const int drow1 = drow0 + 64;
  const int slot = lane & 3;
  const int ch0 = slot ^ ((drow0 >> 1) & 3);
  const int ch1 = slot ^ ((drow1 >> 1) & 3);
  const short* gA0 = &A[(size_t)(bm + drow0) * K + ch0 * 8];
  const short* gA1 = &A[(size_t)(bm + drow1) * K + ch1 * 8];
  const short* gB0 = &B[(size_t)(bn + drow0) * K + ch0 * 8];
  const short* gB1 = &B[(size_t)(bn + drow1) * K + ch1 * 8];
  const int dA0 = (w * 16) * 32, dA1 = (64 + w * 16) * 32;

  const int wm = (w & 1) * 64, wn = (w >> 1) * 64;
  int offA[4], offB[4];
#pragma unroll
  for (int i = 0; i < 4; ++i) {
    int R = wm + i * 16 + l16;
    offA[i] = R * 32 + (quad ^ ((R >> 1) & 3)) * 8;
    int Rb = wn + i * 16 + l16;
    offB[i] = Rb * 32 + (quad ^ ((Rb >> 1) & 3)) * 8;
  }

  f32x4 acc[4][4];
#pragma unroll
  for (int i = 0; i < 4; ++i)
#pragma unroll
    for (int j = 0; j < 4; ++j)
#pragma unroll
      for (int e = 0; e < 4; ++e) acc[i][j][e] = 0.f;

  const int T = K / 32;
  dma16(gA0, &As[0][dA0]);
  dma16(gA1, &As[0][dA1]);
  dma16(gB0, &Bs[0][dA0]);
  dma16(gB1, &Bs[0][dA1]);
  __syncthreads();

  for (int t = 0; t < T; ++t) {
    const int cur = t & 1, nxt = cur ^ 1;
    if (t + 1 < T) {
      const int ko = (t + 1) * 32;
      dma16(gA0 + ko, &As[nxt][dA0]);
      dma16(gA1 + ko, &As[nxt][dA1]);
      dma16(gB0 + ko, &Bs[nxt][dA0]);
      dma16(gB1 + ko, &Bs[nxt][dA1]);
    }
    short8 af[4], bf[4];
#pragma unroll
    for (int i = 0; i < 4; ++i) af[i] = *(const short8*)&As[cur][offA[i]];
#pragma unroll
    for (int j = 0; j < 4; ++j) bf[j] = *(const short8*)&Bs[cur][offB[j]];
#pragma unroll
    for (int i = 0; i < 4; ++i)
#pragma unroll
      for (int j = 0; j < 4; ++j)
        acc[i][j] = __builtin_amdgcn_mfma_f32_16x16x32_bf16(af[i], bf[j], acc[i][j], 0, 0, 0);
    __syncthreads();
  }

#pragma unroll
  for (int i = 0; i < 4; ++i) {
#pragma unroll
    for (int j = 0; j < 4; ++j) {
      const int col = bn + wn + j * 16 + l16;
      const float bv = bias[col];
      const int row0 = bm + wm + i * 16 + quad * 4;
#pragma unroll
      for (int e = 0; e < 4; ++e)
        C[(size_t)(row0 + e) * N + col] = acc[i][j][e] + bv;
    }
  }
}

// ---------------------------------------------------------------------------
// RoPE on Q + repack to head-major bf16, prescaled by 0.125*log2(e).
// ---------------------------------------------------------------------------
#define QSCALE 0.18033688011112042f   // (1/8) * log2(e)

__global__ __launch_bounds__(256) void rope_q_pack(
    const float* __restrict__ Qf, short* __restrict__ Qb) {
  const int g = blockIdx.x * 256 + threadIdx.x;   // pair index
  const int s = g >> 10;
  const int rem = g & 1023;
  const int h = rem >> 5, j = rem & 31;
  const double e = (2.0 * j) / 64.0;
  const float freq = (float)pow(10000.0, -e);
  const float theta = (float)s * freq;            // fp32, matches np bits
  float sn, cs;
  fast_sincos(theta, sn, cs);
  const float* p = &Qf[(size_t)s * D_MODEL + h * 64 + 2 * j];
  const float x1 = p[0], x2 = p[1];
  short2 o;
  o.x = bf16_rne((x1 * cs - x2 * sn) * QSCALE);
  o.y = bf16_rne((x1 * sn + x2 * cs) * QSCALE);
  *(short2*)&Qb[((size_t)h * S_LEN + s) * 64 + 2 * j] = o;
}

// ---------------------------------------------------------------------------
// RoPE on K -> Kb[kvh][s][64] bf16; V -> Vt[kvh][64][S] bf16 (transposed).
// ---------------------------------------------------------------------------
__global__ __launch_bounds__(256) void rope_kv_pack(
    const float* __restrict__ KVf, short* __restrict__ Kb,
    short* __restrict__ Vt) {
  const int st = blockIdx.x, kvh = blockIdx.y;
  const int tid = threadIdx.x;
  __shared__ short Vtile[64][72];

  {
    const int sr = tid >> 2, sc = (tid & 3) * 16;
    const int s = st * 64 + sr;
    const float* kg = &KVf[(size_t)s * 1024 + kvh * 64 + sc];
    short tmp[16];
#pragma unroll
    for (int i = 0; i < 8; ++i) {
      const int j = (sc >> 1) + i;
      const double e = (2.0 * j) / 64.0;
      const float freq = (float)pow(10000.0, -e);
      const float theta = (float)s * freq;
      float sn, cs;
      fast_sincos(theta, sn, cs);
      const float x1 = kg[2 * i], x2 = kg[2 * i + 1];
      tmp[2 * i]     = bf16_rne(x1 * cs - x2 * sn);
      tmp[2 * i + 1] = bf16_rne(x1 * sn + x2 * cs);
    }
    short* out = &Kb[((size_t)kvh * S_LEN + s) * 64 + sc];
    *(short8*)&out[0] = *(short8*)&tmp[0];
    *(short8*)&out[8] = *(short8*)&tmp[8];
  }

  {
    const int sr = tid >> 2, sc = (tid & 3) * 16;
    const float* vg = &KVf[(size_t)(st * 64 + sr) * 1024 + 512 + kvh * 64 + sc];
    short tmp[16];
#pragma unroll
    for (int c = 0; c < 16; c += 4) {
      float4 v = *(const float4*)&vg[c];
      tmp[c + 0] = bf16_rne(v.x);
      tmp[c + 1] = bf16_rne(v.y);
      tmp[c + 2] = bf16_rne(v.z);
      tmp[c + 3] = bf16_rne(v.w);
    }
    *(short8*)&Vtile[sr][sc]     = *(short8*)&tmp[0];
    *(short8*)&Vtile[sr][sc + 8] = *(short8*)&tmp[8];
  }
  __syncthreads();
  {
    const int d = tid & 63, kchunk = tid >> 6;
    short tmp[16];
#pragma unroll
    for (int k = 0; k < 16; ++k) tmp[k] = Vtile[kchunk * 16 + k][d];
    short* out = &Vt[((size_t)kvh * 64 + d) * S_LEN + st * 64 + kchunk * 16];
    *(short8*)&out[0] = *(short8*)&tmp[0];
    *(short8*)&out[8] = *(short8*)&tmp[8];
  }
}

// ---------------------------------------------------------------------------
// MFMA flash attention v7: fixed-reference softmax, K via LDS DMA dbuf,
// V fragments via GLOBAL register-pipelined loads (Vtb is L2-resident, 2MB).
// V loads for t+1 are issued textually after PV(t) consumes vf - ~a full
// softmax+S-MFMA of latency hiding without occupancy. LDS = 25.6KB ->
// 4 blocks/CU co-resident (grid is exactly 4/CU; launch_bounds(256,4) caps
// VGPR at 128 so the whole grid fits with no 3+1 tail).
// ---------------------------------------------------------------------------
__global__ __launch_bounds__(256, 4) void flash7(
    const short* __restrict__ Qb, const short* __restrict__ Kb,
    const short* __restrict__ Vt, short* __restrict__ Oh) {
  const int qt = blockIdx.x, h = blockIdx.y;
  const int kvh = h >> 2;
  const int tid = threadIdx.x;
  const int w = tid >> 6, lane = tid & 63;
  const int l16 = lane & 15, quad = lane >> 4;

  __shared__ short Ks[2][64 * 64];
  __shared__ short Ps[64 * 72];

  const short* Kh = Kb + (size_t)kvh * S_LEN * 64;
  const short* Vh = Vt + (size_t)kvh * 64 * S_LEN;
  const int qr = qt * 64 + w * 16 + l16;

  short8 qf0 = *(const short8*)&Qb[((size_t)h * S_LEN + qr) * 64 + quad * 8];
  short8 qf1 = *(const short8*)&Qb[((size_t)h * S_LEN + qr) * 64 + 32 + quad * 8];

  short8 ones;
#pragma unroll
  for (int e = 0; e < 8; ++e) ones[e] = (short)0x3F80;   // bf16 1.0

  // ---- K DMA coords: wave w stages rows [w*16, w*16+16) ----
  const int drow = lane >> 3;
  const int ch = (lane & 7) ^ drow;
  const short* gK = &Kh[(size_t)(w * 16 + drow) * 64 + ch * 8];

  // ---- K frag read offsets (shorts): slot = (ks*4+quad) ^ (l16&7) ----
  const int sl0 = quad ^ (l16 & 7);
  int offT[4][2];
#pragma unroll
  for (int m = 0; m < 4; ++m) {
    offT[m][0] = (m * 16 + l16) * 64 + sl0 * 8;
    offT[m][1] = (m * 16 + l16) * 64 + (sl0 ^ 4) * 8;
  }
  const int prow = (w * 16 + l16) * 72;

  // ---- V global frag pointers: row d = m*16+l16, cols t*64 + ks*32 + quad*8
  const short* gV[4];
#pragma unroll
  for (int m = 0; m < 4; ++m)
    gV[m] = &Vh[(size_t)(m * 16 + l16) * S_LEN + quad * 8];

  f32x4 accl;
#pragma unroll
  for (int e = 0; e < 4; ++e) accl[e] = 0.f;
  f32x4 acco[4];
#pragma unroll
  for (int m = 0; m < 4; ++m)
#pragma unroll
    for (int e = 0; e < 4; ++e) acco[m][e] = 0.f;

  // ---- preload: K tile 0 via DMA, V tile 0 into registers ----
  dma16(gK,          &Ks[0][(w * 16) * 64]);
  dma16(gK + 8 * 64, &Ks[0][(w * 16 + 8) * 64]);
  short8 vf[4][2];
#pragma unroll
  for (int m = 0; m < 4; ++m) {
    vf[m][0] = *(const short8*)(gV[m]);
    vf[m][1] = *(const short8*)(gV[m] + 32);
  }
  __syncthreads();

  for (int t = 0; t < 32; ++t) {
    const int cur = t & 1, nxt = cur ^ 1;
    if (t + 1 < 32) {   // prefetch next K tile into the other LDS buffer
      const short* gKn = gK + (t + 1) * 4096;
      dma16(gKn,          &Ks[nxt][(w * 16) * 64]);
      dma16(gKn + 8 * 64, &Ks[nxt][(w * 16 + 8) * 64]);
    }

    // ---- S^T = K.Q^T ----
    const short* kc = Ks[cur];
    f32x4 accs[4];
#pragma unroll
    for (int m = 0; m < 4; ++m)
#pragma unroll
      for (int e = 0; e < 4; ++e) accs[m][e] = 0.f;
#pragma unroll
    for (int m = 0; m < 4; ++m) {
      short8 k0 = *(const short8*)&kc[offT[m][0]];
      short8 k1 = *(const short8*)&kc[offT[m][1]];
      accs[m] = __builtin_amdgcn_mfma_f32_16x16x32_bf16(k0, qf0, accs[m], 0, 0, 0);
      accs[m] = __builtin_amdgcn_mfma_f32_16x16x32_bf16(k1, qf1, accs[m], 0, 0, 0);
    }

    // ---- p = exp2(s), pack to bf16 (truncate) into wave-private Ps ----
#pragma unroll
    for (int m = 0; m < 4; ++m) {
      float p0 = exp2f(accs[m][0]);
      float p1 = exp2f(accs[m][1]);
      float p2 = exp2f(accs[m][2]);
      float p3 = exp2f(accs[m][3]);
      unsigned u01 = __builtin_amdgcn_perm(__float_as_uint(p1), __float_as_uint(p0), 0x07060302u);
      unsigned u23 = __builtin_amdgcn_perm(__float_as_uint(p3), __float_as_uint(p2), 0x07060302u);
      *(uint2*)&Ps[prow + m * 16 + quad * 4] = make_uint2(u01, u23);
    }

    // ---- read P fragments; l += ones.P (MFMA); O^T += V^T.P^T ----
    short8 pf0 = *(const short8*)&Ps[prow + quad * 8];
    short8 pf1 = *(const short8*)&Ps[prow + 32 + quad * 8];
    accl = __builtin_amdgcn_mfma_f32_16x16x32_bf16(ones, pf0, accl, 0, 0, 0);
    accl = __builtin_amdgcn_mfma_f32_16x16x32_bf16(ones, pf1, accl, 0, 0, 0);
#pragma unroll
    for (int m = 0; m < 4; ++m) {
      acco[m] = __builtin_amdgcn_mfma_f32_16x16x32_bf16(vf[m][0], pf0, acco[m], 0, 0, 0);
      acco[m] = __builtin_amdgcn_mfma_f32_16x16x32_bf16(vf[m][1], pf1, acco[m], 0, 0, 0);
    }

    // ---- refill vf for t+1 (after PV consumed it; WAR handled by compiler)
    if (t + 1 < 32) {
      const int vo = (t + 1) * 64;
#pragma unroll
      for (int m = 0; m < 4; ++m) {
        vf[m][0] = *(const short8*)(gV[m] + vo);
        vf[m][1] = *(const short8*)(gV[m] + vo + 32);
      }
    }

    __syncthreads();   // drains K dma(t+1) (vmcnt) + guards buffer swap
  }

  // ---- epilogue: O / l, plain bf16 ----
  const float inv = 1.f / accl[0];
#pragma unroll
  for (int m = 0; m < 4; ++m) {
    short4 h4;
    h4.x = bf16_rne(acco[m][0] * inv);
    h4.y = bf16_rne(acco[m][1] * inv);
    h4.z = bf16_rne(acco[m][2] * inv);
    h4.w = bf16_rne(acco[m][3] * inv);
    const size_t base = (size_t)qr * D_MODEL + h * 64 + m * 16 + quad * 4;
    *(short4*)&Oh[base] = h4;
  }
}

// ---------------------------------------------------------------------------
extern "C" void kernel_launch(void* const* d_in, const int* in_sizes, int n_in,
                              void* d_out, int out_size, void* d_ws, size_t ws_size,
                              hipStream_t stream) {
  const float* x     = (const float*)d_in[0];
  const float* W_q   = (const float*)d_in[1];
  const float* b_q   = (const float*)d_in[2];
  const float* W_kv  = (const float*)d_in[3];
  const float* b_kv  = (const float*)d_in[4];
  const float* W_out = (const float*)d_in[5];
  const float* b_out = (const float*)d_in[6];
  float* out = (float*)d_out;

  char* ws = (char*)d_ws;                        // 64 MB used
  float* Qbuf  = (float*)(ws);                   // 16 MB fp32 [2048,2048]
  float* KVbuf = (float*)(ws + (16u << 20));     //  8 MB fp32 [2048,1024]
  short* xh    = (short*)(ws + (24u << 20));     //  8 MB
  short* Wqh   = (short*)(ws + (32u << 20));     //  8 MB
  short* Wkvh  = (short*)(ws + (40u << 20));     //  4 MB
  short* Woh   = (short*)(ws + (44u << 20));     //  8 MB
  short* Qb    = (short*)(ws + (52u << 20));     //  8 MB bf16 [32][2048][64]
  short* Kb    = (short*)(ws + (60u << 20));     //  2 MB bf16 [8][2048][64]
  short* Vtb   = (short*)(ws + (62u << 20));     //  2 MB bf16 [8][64][2048]
  short* Ath   = xh;   // x dead after gemm_nt1_dual

  // one fused conversion launch: 14M elems / 8 per thr / 256 per blk = 7168
  cvt_all<<<7168, 256, 0, stream>>>(x, xh, W_q, Wqh, W_kv, Wkvh, W_out, Woh);

  gemm_nt1_dual<<<dim3(3072 / 128, 2048 / 128), 256, 0, stream>>>(
      xh, Wqh, Wkvh, b_q, b_kv, Qbuf, KVbuf, 2048, 1024, 2048);

  rope_q_pack<<<(S_LEN * 1024) / 256, 256, 0, stream>>>(Qbuf, Qb);
  rope_kv_pack<<<dim3(S_LEN / 64, KV_HEADS), 256, 0, stream>>>(KVbuf, Kb, Vtb);

  flash7<<<dim3(S_LEN / 64, Q_HEADS), 256, 0, stream>>>(Qb, Kb, Vtb, Ath);

  gemm_nt1_big<<<dim3(2048 / 128, 2048 / 128), 256, 0, stream>>>(
      Ath, Woh, b_out, out, 2048, 2048);
}

// Round 10
// 268.267 us; speedup vs baseline: 1.2591x; 1.2591x over previous
//
#include <hip/hip_runtime.h>
#include <hip/hip_bf16.h>
#include <math.h>

#define S_LEN 2048
#define D_MODEL 2048
#define Q_HEADS 32
#define KV_HEADS 8

typedef __attribute__((ext_vector_type(8))) short short8;   // 8 bf16 = 4 VGPRs
typedef __attribute__((ext_vector_type(4))) float f32x4;

// ---------------------------------------------------------------------------
// helpers
// ---------------------------------------------------------------------------
__device__ __forceinline__ short bf16_rne(float f) {
  unsigned u = __float_as_uint(f);
  unsigned r = (u + 0x7FFFu + ((u >> 16) & 1u)) >> 16;
  return (short)r;
}
// async global->LDS DMA, 16B per lane; lds dest = wave-uniform base + lane*16
__device__ __forceinline__ void dma16(const short* g, short* l) {
  __builtin_amdgcn_global_load_lds(
      (const __attribute__((address_space(1))) void*)g,
      (__attribute__((address_space(3))) void*)l, 16, 0, 0);
}
// hw trig on fp32 theta (radians) via fp64 range reduction to revolutions
__device__ __forceinline__ void fast_sincos(float theta, float& sn, float& cs) {
  double rev = (double)theta * 0.15915494309189535;  // theta / 2pi
  float fr = (float)(rev - floor(rev));
  sn = __builtin_amdgcn_sinf(fr);
  cs = __builtin_amdgcn_cosf(fr);
}
__device__ __forceinline__ void cvt8(const float* src, short* dst, int i) {
  float4 a = *(const float4*)&src[i];
  float4 b = *(const float4*)&src[i + 4];
  short8 h;
  h[0] = bf16_rne(a.x); h[1] = bf16_rne(a.y);
  h[2] = bf16_rne(a.z); h[3] = bf16_rne(a.w);
  h[4] = bf16_rne(b.x); h[5] = bf16_rne(b.y);
  h[6] = bf16_rne(b.z); h[7] = bf16_rne(b.w);
  *(short8*)&dst[i] = h;
}

// ---------------------------------------------------------------------------
// Fused fp32->bf16 conversion of x, W_q, W_kv, W_out in ONE launch.
// ---------------------------------------------------------------------------
#define NM (2048 * 2048)
#define NKV (1024 * 2048)

__global__ __launch_bounds__(256) void cvt_all(
    const float* __restrict__ x,    short* __restrict__ xh,
    const float* __restrict__ wq,   short* __restrict__ wqh,
    const float* __restrict__ wkv,  short* __restrict__ wkvh,
    const float* __restrict__ wo,   short* __restrict__ woh) {
  int i = (blockIdx.x * 256 + threadIdx.x) * 8;
  if (i < NM) { cvt8(x, xh, i); return; }
  i -= NM;
  if (i < NM) { cvt8(wq, wqh, i); return; }
  i -= NM;
  if (i < NKV) { cvt8(wkv, wkvh, i); return; }
  i -= NKV;
  cvt8(wo, woh, i);
}

// ---------------------------------------------------------------------------
// NT1 GEMM with dual output (Q | KV concat on the N axis), DMA staging,
// double-buffered (prefetch t+1 overlaps MFMA of t; barrier drains vmcnt).
// ---------------------------------------------------------------------------
__global__ __launch_bounds__(256) void gemm_nt1_dual(
    const short* __restrict__ Ah,
    const short* __restrict__ Bq, const short* __restrict__ Bkv,
    const float* __restrict__ bq, const float* __restrict__ bkv,
    float* __restrict__ Cq, float* __restrict__ Ckv,
    int Nq, int Nkv, int K) {
  __shared__ short As[2][128 * 32];
  __shared__ short Bs[2][128 * 32];
  const int tid = threadIdx.x;
  const int w = tid >> 6, lane = tid & 63;
  const int l16 = lane & 15, quad = lane >> 4;
  const int bm = blockIdx.y * 128;
  const int bnG = blockIdx.x * 128;

  const short* Bsrc; const float* bias; float* Cp; int pitch; int bn;
  if (bnG < Nq) { Bsrc = Bq;  bias = bq;  Cp = Cq;  pitch = Nq;  bn = bnG; }
  else          { Bsrc = Bkv; bias = bkv; Cp = Ckv; pitch = Nkv; bn = bnG - Nq; }

  const int drow0 = w * 16 + (lane >> 2);
  const int drow1 = drow0 + 64;
  const int slot = lane & 3;
  const int ch0 = slot ^ ((drow0 >> 1) & 3);
  const int ch1 = slot ^ ((drow1 >> 1) & 3);
  const short* gA0 = &Ah[(size_t)(bm + drow0) * K + ch0 * 8];
  const short* gA1 = &Ah[(size_t)(bm + drow1) * K + ch1 * 8];
  const short* gB0 = &Bsrc[(size_t)(bn + drow0) * K + ch0 * 8];
  const short* gB1 = &Bsrc[(size_t)(bn + drow1) * K + ch1 * 8];
  const int dA0 = (w * 16) * 32, dA1 = (64 + w * 16) * 32;

  const int wm = (w & 1) * 64, wn = (w >> 1) * 64;
  int offA[4], offB[4];
#pragma unroll
  for (int i = 0; i < 4; ++i) {
    int R = wm + i * 16 + l16;
    offA[i] = R * 32 + (quad ^ ((R >> 1) & 3)) * 8;
    int Rb = wn + i * 16 + l16;
    offB[i] = Rb * 32 + (quad ^ ((Rb >> 1) & 3)) * 8;
  }

  f32x4 acc[4][4];
#pragma unroll
  for (int i = 0; i < 4; ++i)
#pragma unroll
    for (int j = 0; j < 4; ++j)
#pragma unroll
      for (int e = 0; e < 4; ++e) acc[i][j][e] = 0.f;

  const int T = K / 32;
  dma16(gA0, &As[0][dA0]);
  dma16(gA1, &As[0][dA1]);
  dma16(gB0, &Bs[0][dA0]);
  dma16(gB1, &Bs[0][dA1]);
  __syncthreads();

  for (int t = 0; t < T; ++t) {
    const int cur = t & 1, nxt = cur ^ 1;
    if (t + 1 < T) {
      const int ko = (t + 1) * 32;
      dma16(gA0 + ko, &As[nxt][dA0]);
      dma16(gA1 + ko, &As[nxt][dA1]);
      dma16(gB0 + ko, &Bs[nxt][dA0]);
      dma16(gB1 + ko, &Bs[nxt][dA1]);
    }
    short8 af[4], bf[4];
#pragma unroll
    for (int i = 0; i < 4; ++i) af[i] = *(const short8*)&As[cur][offA[i]];
#pragma unroll
    for (int j = 0; j < 4; ++j) bf[j] = *(const short8*)&Bs[cur][offB[j]];
#pragma unroll
    for (int i = 0; i < 4; ++i)
#pragma unroll
      for (int j = 0; j < 4; ++j)
        acc[i][j] = __builtin_amdgcn_mfma_f32_16x16x32_bf16(af[i], bf[j], acc[i][j], 0, 0, 0);
    __syncthreads();   // reads of cur done; dma(t+1) drained
  }

#pragma unroll
  for (int i = 0; i < 4; ++i) {
#pragma unroll
    for (int j = 0; j < 4; ++j) {
      const int col = bn + wn + j * 16 + l16;
      const float bv = bias[col];
      const int row0 = bm + wm + i * 16 + quad * 4;
#pragma unroll
      for (int e = 0; e < 4; ++e)
        Cp[(size_t)(row0 + e) * pitch + col] = acc[i][j][e] + bv;
    }
  }
}

// ---------------------------------------------------------------------------
// Single-output bf16 NT GEMM, BM=BN=128 (out-projection).
// ---------------------------------------------------------------------------
__global__ __launch_bounds__(256) void gemm_nt1_big(
    const short* __restrict__ A, const short* __restrict__ B,
    const float* __restrict__ bias, float* __restrict__ C,
    int N, int K) {
  __shared__ short As[2][128 * 32];
  __shared__ short Bs[2][128 * 32];
  const int tid = threadIdx.x;
  const int w = tid >> 6, lane = tid & 63;
  const int l16 = lane & 15, quad = lane >> 4;
  const int bm = blockIdx.y * 128;
  const int bn = blockIdx.x * 128;

  const int drow0 = w * 16 + (lane >> 2);
  const int drow1 = drow0 + 64;
  const int slot = lane & 3;
  const int ch0 = slot ^ ((drow0 >> 1) & 3);
  const int ch1 = slot ^ ((drow1 >> 1) & 3);
  const short* gA0 = &A[(size_t)(bm + drow0) * K + ch0 * 8];
  const short* gA1 = &A[(size_t)(bm + drow1) * K + ch1 * 8];
  const short* gB0 = &B[(size_t)(bn + drow0) * K + ch0 * 8];
  const short* gB1 = &B[(size_t)(bn + drow1) * K + ch1 * 8];
  const int dA0 = (w * 16) * 32, dA1 = (64 + w * 16) * 32;

  const int wm = (w & 1) * 64, wn = (w >> 1) * 64;
  int offA[4], offB[4];
#pragma unroll
  for (int i = 0; i < 4; ++i) {
    int R = wm + i * 16 + l16;
    offA[i] = R * 32 + (quad ^ ((R >> 1) & 3)) * 8;
    int Rb = wn + i * 16 + l16;
    offB[i] = Rb * 32 + (quad ^ ((Rb >> 1) & 3)) * 8;
  }

  f32x4 acc[4][4];
#pragma unroll
  for (int i = 0; i < 4; ++i)
#pragma unroll
    for (int j = 0; j < 4; ++j)
#pragma unroll
      for (int e = 0; e < 4; ++e) acc[i][j][e] = 0.f;

  const int T = K / 32;
  dma16(gA0, &As[0][dA0]);
  dma16(gA1, &As[0][dA1]);
  dma16(gB0, &Bs[0][dA0]);
  dma16(gB1, &Bs[0][dA1]);
  __syncthreads();

  for (int t = 0; t < T; ++t) {
    const int cur = t & 1, nxt = cur ^ 1;
    if (t + 1 < T) {
      const int ko = (t + 1) * 32;
      dma16(gA0 + ko, &As[nxt][dA0]);
      dma16(gA1 + ko, &As[nxt][dA1]);
      dma16(gB0 + ko, &Bs[nxt][dA0]);
      dma16(gB1 + ko, &Bs[nxt][dA1]);
    }
    short8 af[4], bf[4];
#pragma unroll
    for (int i = 0; i < 4; ++i) af[i] = *(const short8*)&As[cur][offA[i]];
#pragma unroll
    for (int j = 0; j < 4; ++j) bf[j] = *(const short8*)&Bs[cur][offB[j]];
#pragma unroll
    for (int i = 0; i < 4; ++i)
#pragma unroll
      for (int j = 0; j < 4; ++j)
        acc[i][j] = __builtin_amdgcn_mfma_f32_16x16x32_bf16(af[i], bf[j], acc[i][j], 0, 0, 0);
    __syncthreads();
  }

#pragma unroll
  for (int i = 0; i < 4; ++i) {
#pragma unroll
    for (int j = 0; j < 4; ++j) {
      const int col = bn + wn + j * 16 + l16;
      const float bv = bias[col];
      const int row0 = bm + wm + i * 16 + quad * 4;
#pragma unroll
      for (int e = 0; e < 4; ++e)
        C[(size_t)(row0 + e) * N + col] = acc[i][j][e] + bv;
    }
  }
}

// ---------------------------------------------------------------------------
// RoPE on Q + repack to head-major bf16, prescaled by 0.125*log2(e).
// ---------------------------------------------------------------------------
#define QSCALE 0.18033688011112042f   // (1/8) * log2(e)

__global__ __launch_bounds__(256) void rope_q_pack(
    const float* __restrict__ Qf, short* __restrict__ Qb) {
  const int g = blockIdx.x * 256 + threadIdx.x;   // pair index
  const int s = g >> 10;
  const int rem = g & 1023;
  const int h = rem >> 5, j = rem & 31;
  const double e = (2.0 * j) / 64.0;
  const float freq = (float)pow(10000.0, -e);
  const float theta = (float)s * freq;            // fp32, matches np bits
  float sn, cs;
  fast_sincos(theta, sn, cs);
  const float* p = &Qf[(size_t)s * D_MODEL + h * 64 + 2 * j];
  const float x1 = p[0], x2 = p[1];
  short2 o;
  o.x = bf16_rne((x1 * cs - x2 * sn) * QSCALE);
  o.y = bf16_rne((x1 * sn + x2 * cs) * QSCALE);
  *(short2*)&Qb[((size_t)h * S_LEN + s) * 64 + 2 * j] = o;
}

// ---------------------------------------------------------------------------
// RoPE on K -> Kb[kvh][s][64] bf16; V -> Vt[kvh][64][S] bf16 (transposed).
// ---------------------------------------------------------------------------
__global__ __launch_bounds__(256) void rope_kv_pack(
    const float* __restrict__ KVf, short* __restrict__ Kb,
    short* __restrict__ Vt) {
  const int st = blockIdx.x, kvh = blockIdx.y;
  const int tid = threadIdx.x;
  __shared__ short Vtile[64][72];

  {
    const int sr = tid >> 2, sc = (tid & 3) * 16;
    const int s = st * 64 + sr;
    const float* kg = &KVf[(size_t)s * 1024 + kvh * 64 + sc];
    short tmp[16];
#pragma unroll
    for (int i = 0; i < 8; ++i) {
      const int j = (sc >> 1) + i;
      const double e = (2.0 * j) / 64.0;
      const float freq = (float)pow(10000.0, -e);
      const float theta = (float)s * freq;
      float sn, cs;
      fast_sincos(theta, sn, cs);
      const float x1 = kg[2 * i], x2 = kg[2 * i + 1];
      tmp[2 * i]     = bf16_rne(x1 * cs - x2 * sn);
      tmp[2 * i + 1] = bf16_rne(x1 * sn + x2 * cs);
    }
    short* out = &Kb[((size_t)kvh * S_LEN + s) * 64 + sc];
    *(short8*)&out[0] = *(short8*)&tmp[0];
    *(short8*)&out[8] = *(short8*)&tmp[8];
  }

  {
    const int sr = tid >> 2, sc = (tid & 3) * 16;
    const float* vg = &KVf[(size_t)(st * 64 + sr) * 1024 + 512 + kvh * 64 + sc];
    short tmp[16];
#pragma unroll
    for (int c = 0; c < 16; c += 4) {
      float4 v = *(const float4*)&vg[c];
      tmp[c + 0] = bf16_rne(v.x);
      tmp[c + 1] = bf16_rne(v.y);
      tmp[c + 2] = bf16_rne(v.z);
      tmp[c + 3] = bf16_rne(v.w);
    }
    *(short8*)&Vtile[sr][sc]     = *(short8*)&tmp[0];
    *(short8*)&Vtile[sr][sc + 8] = *(short8*)&tmp[8];
  }
  __syncthreads();
  {
    const int d = tid & 63, kchunk = tid >> 6;
    short tmp[16];
#pragma unroll
    for (int k = 0; k < 16; ++k) tmp[k] = Vtile[kchunk * 16 + k][d];
    short* out = &Vt[((size_t)kvh * 64 + d) * S_LEN + st * 64 + kchunk * 16];
    *(short8*)&out[0] = *(short8*)&tmp[0];
    *(short8*)&out[8] = *(short8*)&tmp[8];
  }
}

// ---------------------------------------------------------------------------
// MFMA flash attention v8 = flash6 dataflow (K and V both LDS, DMA dbuf,
// ONE barrier/tile - R9 showed per-lane global loads can't span the barrier's
// vmcnt(0) drain) + Ps compressed to stride 64 with a 16B-chunk XOR swizzle
// (slot = chunk ^ ((l16&7)<<1); even XOR preserves intra-16B order).
// LDS = 16384 + 16384 + 8192 = 40960 B exactly -> 4 blocks/CU, no 3+1 tail.
// ---------------------------------------------------------------------------
__global__ __launch_bounds__(256, 4) void flash8(
    const short* __restrict__ Qb, const short* __restrict__ Kb,
    const short* __restrict__ Vt, short* __restrict__ Oh) {
  const int qt = blockIdx.x, h = blockIdx.y;
  const int kvh = h >> 2;
  const int tid = threadIdx.x;
  const int w = tid >> 6, lane = tid & 63;
  const int l16 = lane & 15, quad = lane >> 4;

  __shared__ short Ks[2][64 * 64];
  __shared__ short Vs[2][64 * 64];
  __shared__ short Ps[64 * 64];

  const short* Kh = Kb + (size_t)kvh * S_LEN * 64;
  const short* Vh = Vt + (size_t)kvh * 64 * S_LEN;
  const int qr = qt * 64 + w * 16 + l16;

  short8 qf0 = *(const short8*)&Qb[((size_t)h * S_LEN + qr) * 64 + quad * 8];
  short8 qf1 = *(const short8*)&Qb[((size_t)h * S_LEN + qr) * 64 + 32 + quad * 8];

  short8 ones;
#pragma unroll
  for (int e = 0; e < 8; ++e) ones[e] = (short)0x3F80;   // bf16 1.0

  // ---- DMA coords: wave w stages rows [w*16, w*16+16) ----
  const int drow = lane >> 3;
  const int ch = (lane & 7) ^ drow;
  const short* gK = &Kh[(size_t)(w * 16 + drow) * 64 + ch * 8];
  const short* gV = &Vh[(size_t)(w * 16 + drow) * S_LEN + ch * 8];

  // ---- K/V frag read offsets: slot = (ks*4+quad) ^ (l16&7) ----
  const int sl0 = quad ^ (l16 & 7);
  int offT[4][2];
#pragma unroll
  for (int m = 0; m < 4; ++m) {
    offT[m][0] = (m * 16 + l16) * 64 + sl0 * 8;
    offT[m][1] = (m * 16 + l16) * 64 + (sl0 ^ 4) * 8;
  }

  // ---- Ps coords (stride 64, 8B-granule XOR swizzle, even bits only) ----
  const int prow = (w * 16 + l16) * 64;
  const int pswz = (l16 & 7) << 1;
  int pwr[4];            // write: granule 4m+quad -> slot
#pragma unroll
  for (int m = 0; m < 4; ++m) pwr[m] = prow + ((4 * m + quad) ^ pswz) * 4;
  const int prd0 = prow + ((2 * quad) ^ pswz) * 4;       // granules 2q,2q+1
  const int prd1 = prow + ((8 + 2 * quad) ^ pswz) * 4;   // granules 8+2q,+1

  f32x4 accl;
#pragma unroll
  for (int e = 0; e < 4; ++e) accl[e] = 0.f;
  f32x4 acco[4];
#pragma unroll
  for (int m = 0; m < 4; ++m)
#pragma unroll
    for (int e = 0; e < 4; ++e) acco[m][e] = 0.f;

  dma16(gK,               &Ks[0][(w * 16) * 64]);
  dma16(gK + 8 * 64,      &Ks[0][(w * 16 + 8) * 64]);
  dma16(gV,               &Vs[0][(w * 16) * 64]);
  dma16(gV + 8 * S_LEN,   &Vs[0][(w * 16 + 8) * 64]);
  __syncthreads();

  for (int t = 0; t < 32; ++t) {
    const int cur = t & 1, nxt = cur ^ 1;
    if (t + 1 < 32) {
      const short* gKn = gK + (t + 1) * 4096;
      const short* gVn = gV + (t + 1) * 64;
      dma16(gKn,             &Ks[nxt][(w * 16) * 64]);
      dma16(gKn + 8 * 64,    &Ks[nxt][(w * 16 + 8) * 64]);
      dma16(gVn,             &Vs[nxt][(w * 16) * 64]);
      dma16(gVn + 8 * S_LEN, &Vs[nxt][(w * 16 + 8) * 64]);
    }

    // ---- S^T = K.Q^T ----
    const short* kc = Ks[cur];
    f32x4 accs[4];
#pragma unroll
    for (int m = 0; m < 4; ++m)
#pragma unroll
      for (int e = 0; e < 4; ++e) accs[m][e] = 0.f;
#pragma unroll
    for (int m = 0; m < 4; ++m) {
      short8 k0 = *(const short8*)&kc[offT[m][0]];
      short8 k1 = *(const short8*)&kc[offT[m][1]];
      accs[m] = __builtin_amdgcn_mfma_f32_16x16x32_bf16(k0, qf0, accs[m], 0, 0, 0);
      accs[m] = __builtin_amdgcn_mfma_f32_16x16x32_bf16(k1, qf1, accs[m], 0, 0, 0);
    }

    // ---- p = exp2(s), pack to bf16 (truncate) into wave-private Ps ----
#pragma unroll
    for (int m = 0; m < 4; ++m) {
      float p0 = exp2f(accs[m][0]);
      float p1 = exp2f(accs[m][1]);
      float p2 = exp2f(accs[m][2]);
      float p3 = exp2f(accs[m][3]);
      unsigned u01 = __builtin_amdgcn_perm(__float_as_uint(p1), __float_as_uint(p0), 0x07060302u);
      unsigned u23 = __builtin_amdgcn_perm(__float_as_uint(p3), __float_as_uint(p2), 0x07060302u);
      *(uint2*)&Ps[pwr[m]] = make_uint2(u01, u23);
    }

    // ---- read P fragments; l += ones.P (MFMA); O^T += V^T.P^T ----
    short8 pf0 = *(const short8*)&Ps[prd0];
    short8 pf1 = *(const short8*)&Ps[prd1];
    accl = __builtin_amdgcn_mfma_f32_16x16x32_bf16(ones, pf0, accl, 0, 0, 0);
    accl = __builtin_amdgcn_mfma_f32_16x16x32_bf16(ones, pf1, accl, 0, 0, 0);
    const short* vc = Vs[cur];
#pragma unroll
    for (int m = 0; m < 4; ++m) {
      short8 v0 = *(const short8*)&vc[offT[m][0]];
      short8 v1 = *(const short8*)&vc[offT[m][1]];
      acco[m] = __builtin_amdgcn_mfma_f32_16x16x32_bf16(v0, pf0, acco[m], 0, 0, 0);
      acco[m] = __builtin_amdgcn_mfma_f32_16x16x32_bf16(v1, pf1, acco[m], 0, 0, 0);
    }

    __syncthreads();   // drains dma(t+1) (vmcnt) + guards buffer swap
  }

  // ---- epilogue: O / l, plain bf16 ----
  const float inv = 1.f / accl[0];
#pragma unroll
  for (int m = 0; m < 4; ++m) {
    short4 h4;
    h4.x = bf16_rne(acco[m][0] * inv);
    h4.y = bf16_rne(acco[m][1] * inv);
    h4.z = bf16_rne(acco[m][2] * inv);
    h4.w = bf16_rne(acco[m][3] * inv);
    const size_t base = (size_t)qr * D_MODEL + h * 64 + m * 16 + quad * 4;
    *(short4*)&Oh[base] = h4;
  }
}

// ---------------------------------------------------------------------------
extern "C" void kernel_launch(void* const* d_in, const int* in_sizes, int n_in,
                              void* d_out, int out_size, void* d_ws, size_t ws_size,
                              hipStream_t stream) {
  const float* x     = (const float*)d_in[0];
  const float* W_q   = (const float*)d_in[1];
  const float* b_q   = (const float*)d_in[2];
  const float* W_kv  = (const float*)d_in[3];
  const float* b_kv  = (const float*)d_in[4];
  const float* W_out = (const float*)d_in[5];
  const float* b_out = (const float*)d_in[6];
  float* out = (float*)d_out;

  char* ws = (char*)d_ws;                        // 64 MB used
  float* Qbuf  = (float*)(ws);                   // 16 MB fp32 [2048,2048]
  float* KVbuf = (float*)(ws + (16u << 20));     //  8 MB fp32 [2048,1024]
  short* xh    = (short*)(ws + (24u << 20));     //  8 MB
  short* Wqh   = (short*)(ws + (32u << 20));     //  8 MB
  short* Wkvh  = (short*)(ws + (40u << 20));     //  4 MB
  short* Woh   = (short*)(ws + (44u << 20));     //  8 MB
  short* Qb    = (short*)(ws + (52u << 20));     //  8 MB bf16 [32][2048][64]
  short* Kb    = (short*)(ws + (60u << 20));     //  2 MB bf16 [8][2048][64]
  short* Vtb   = (short*)(ws + (62u << 20));     //  2 MB bf16 [8][64][2048]
  short* Ath   = xh;   // x dead after gemm_nt1_dual

  // one fused conversion launch: 14M elems / 8 per thr / 256 per blk = 7168
  cvt_all<<<7168, 256, 0, stream>>>(x, xh, W_q, Wqh, W_kv, Wkvh, W_out, Woh);

  gemm_nt1_dual<<<dim3(3072 / 128, 2048 / 128), 256, 0, stream>>>(
      xh, Wqh, Wkvh, b_q, b_kv, Qbuf, KVbuf, 2048, 1024, 2048);

  rope_q_pack<<<(S_LEN * 1024) / 256, 256, 0, stream>>>(Qbuf, Qb);
  rope_kv_pack<<<dim3(S_LEN / 64, KV_HEADS), 256, 0, stream>>>(KVbuf, Kb, Vtb);

  flash8<<<dim3(S_LEN / 64, Q_HEADS), 256, 0, stream>>>(Qb, Kb, Vtb, Ath);

  gemm_nt1_big<<<dim3(2048 / 128, 2048 / 128), 256, 0, stream>>>(
      Ath, Woh, b_out, out, 2048, 2048);
}

// Round 11
// 264.230 us; speedup vs baseline: 1.2783x; 1.0153x over previous
//
#include <hip/hip_runtime.h>
#include <hip/hip_bf16.h>
#include <math.h>

#define S_LEN 2048
#define D_MODEL 2048
#define Q_HEADS 32
#define KV_HEADS 8

typedef __attribute__((ext_vector_type(8))) short short8;   // 8 bf16 = 4 VGPRs
typedef __attribute__((ext_vector_type(4))) float f32x4;

// ---------------------------------------------------------------------------
// helpers
// ---------------------------------------------------------------------------
__device__ __forceinline__ short bf16_rne(float f) {
  unsigned u = __float_as_uint(f);
  unsigned r = (u + 0x7FFFu + ((u >> 16) & 1u)) >> 16;
  return (short)r;
}
// async global->LDS DMA, 16B per lane; lds dest = wave-uniform base + lane*16
__device__ __forceinline__ void dma16(const short* g, short* l) {
  __builtin_amdgcn_global_load_lds(
      (const __attribute__((address_space(1))) void*)g,
      (__attribute__((address_space(3))) void*)l, 16, 0, 0);
}
// hw trig on fp32 theta (radians) via fp64 range reduction to revolutions
__device__ __forceinline__ void fast_sincos(float theta, float& sn, float& cs) {
  double rev = (double)theta * 0.15915494309189535;  // theta / 2pi
  float fr = (float)(rev - floor(rev));
  sn = __builtin_amdgcn_sinf(fr);
  cs = __builtin_amdgcn_cosf(fr);
}
__device__ __forceinline__ void cvt8(const float* src, short* dst, int i) {
  float4 a = *(const float4*)&src[i];
  float4 b = *(const float4*)&src[i + 4];
  short8 h;
  h[0] = bf16_rne(a.x); h[1] = bf16_rne(a.y);
  h[2] = bf16_rne(a.z); h[3] = bf16_rne(a.w);
  h[4] = bf16_rne(b.x); h[5] = bf16_rne(b.y);
  h[6] = bf16_rne(b.z); h[7] = bf16_rne(b.w);
  *(short8*)&dst[i] = h;
}

// ---------------------------------------------------------------------------
// Fused fp32->bf16 conversion of x, W_q, W_kv, W_out in ONE launch.
// Block 0 additionally computes the 32 RoPE frequencies (double pow, rounded
// once to fp32 - bit-identical to the per-thread pow it replaces).
// ---------------------------------------------------------------------------
#define NM (2048 * 2048)
#define NKV (1024 * 2048)

__global__ __launch_bounds__(256) void cvt_all(
    const float* __restrict__ x,    short* __restrict__ xh,
    const float* __restrict__ wq,   short* __restrict__ wqh,
    const float* __restrict__ wkv,  short* __restrict__ wkvh,
    const float* __restrict__ wo,   short* __restrict__ woh,
    float* __restrict__ freqTab) {
  if (blockIdx.x == 0 && threadIdx.x < 32) {
    const double e = (2.0 * threadIdx.x) / 64.0;
    freqTab[threadIdx.x] = (float)pow(10000.0, -e);
  }
  int i = (blockIdx.x * 256 + threadIdx.x) * 8;
  if (i < NM) { cvt8(x, xh, i); return; }
  i -= NM;
  if (i < NM) { cvt8(wq, wqh, i); return; }
  i -= NM;
  if (i < NKV) { cvt8(wkv, wkvh, i); return; }
  i -= NKV;
  cvt8(wo, woh, i);
}

// ---------------------------------------------------------------------------
// NT1 GEMM, dual output (Q | KV on the N axis), BM=128 BN=64 -> 768 blocks
// = 3.0 blocks/CU (12 waves/CU: R10's 384-block/1.5-per-CU version spent half
// its time in a half-empty second round). DMA staging, double-buffered.
// ---------------------------------------------------------------------------
__global__ __launch_bounds__(256) void gemm_nt1_dual(
    const short* __restrict__ Ah,
    const short* __restrict__ Bq, const short* __restrict__ Bkv,
    const float* __restrict__ bq, const float* __restrict__ bkv,
    float* __restrict__ Cq, float* __restrict__ Ckv,
    int Nq, int Nkv, int K) {
  __shared__ short As[2][128 * 32];
  __shared__ short Bs[2][64 * 32];
  const int tid = threadIdx.x;
  const int w = tid >> 6, lane = tid & 63;
  const int l16 = lane & 15, quad = lane >> 4;
  const int bm = blockIdx.y * 128;
  const int bnG = blockIdx.x * 64;

  const short* Bsrc; const float* bias; float* Cp; int pitch; int bn;
  if (bnG < Nq) { Bsrc = Bq;  bias = bq;  Cp = Cq;  pitch = Nq;  bn = bnG; }
  else          { Bsrc = Bkv; bias = bkv; Cp = Ckv; pitch = Nkv; bn = bnG - Nq; }

  const int drow0 = w * 16 + (lane >> 2);
  const int drow1 = drow0 + 64;
  const int slot = lane & 3;
  const int ch0 = slot ^ ((drow0 >> 1) & 3);
  const int ch1 = slot ^ ((drow1 >> 1) & 3);
  const size_t a0 = (size_t)(bm + drow0) * K + ch0 * 8;
  const size_t a1 = (size_t)(bm + drow1) * K + ch1 * 8;
  const size_t b0 = (size_t)(bn + drow0) * K + ch0 * 8;
  const int dA0 = (w * 16) * 32, dA1 = (64 + w * 16) * 32;

  const int wm = (w & 1) * 64, wn = (w >> 1) * 32;
  int offA[4], offB[2];
#pragma unroll
  for (int i = 0; i < 4; ++i) {
    int R = wm + i * 16 + l16;
    offA[i] = R * 32 + (quad ^ ((R >> 1) & 3)) * 8;
  }
#pragma unroll
  for (int j = 0; j < 2; ++j) {
    int R = wn + j * 16 + l16;
    offB[j] = R * 32 + (quad ^ ((R >> 1) & 3)) * 8;
  }

  f32x4 acc[4][2];
#pragma unroll
  for (int i = 0; i < 4; ++i)
#pragma unroll
    for (int j = 0; j < 2; ++j)
#pragma unroll
      for (int e = 0; e < 4; ++e) acc[i][j][e] = 0.f;

  const int T = K / 32;
  dma16(Ah + a0, &As[0][dA0]);
  dma16(Ah + a1, &As[0][dA1]);
  dma16(Bsrc + b0, &Bs[0][dA0]);
  __syncthreads();

  for (int t = 0; t < T; ++t) {
    const int cur = t & 1, nxt = cur ^ 1;
    if (t + 1 < T) {
      const int ko = (t + 1) * 32;
      dma16(Ah + a0 + ko, &As[nxt][dA0]);
      dma16(Ah + a1 + ko, &As[nxt][dA1]);
      dma16(Bsrc + b0 + ko, &Bs[nxt][dA0]);
    }
    short8 af[4], bf[2];
#pragma unroll
    for (int i = 0; i < 4; ++i) af[i] = *(const short8*)&As[cur][offA[i]];
#pragma unroll
    for (int j = 0; j < 2; ++j) bf[j] = *(const short8*)&Bs[cur][offB[j]];
#pragma unroll
    for (int i = 0; i < 4; ++i)
#pragma unroll
      for (int j = 0; j < 2; ++j)
        acc[i][j] = __builtin_amdgcn_mfma_f32_16x16x32_bf16(af[i], bf[j], acc[i][j], 0, 0, 0);
    __syncthreads();
  }

#pragma unroll
  for (int i = 0; i < 4; ++i) {
#pragma unroll
    for (int j = 0; j < 2; ++j) {
      const int col = bn + wn + j * 16 + l16;
      const float bv = bias[col];
      const int row0 = bm + wm + i * 16 + quad * 4;
#pragma unroll
      for (int e = 0; e < 4; ++e)
        Cp[(size_t)(row0 + e) * pitch + col] = acc[i][j][e] + bv;
    }
  }
}

// ---------------------------------------------------------------------------
// Single-output bf16 NT GEMM, BM=BN=128 (out-projection) - unchanged.
// ---------------------------------------------------------------------------
__global__ __launch_bounds__(256) void gemm_nt1_big(
    const short* __restrict__ A, const short* __restrict__ B,
    const float* __restrict__ bias, float* __restrict__ C,
    int N, int K) {
  __shared__ short As[2][128 * 32];
  __shared__ short Bs[2][128 * 32];
  const int tid = threadIdx.x;
  const int w = tid >> 6, lane = tid & 63;
  const int l16 = lane & 15, quad = lane >> 4;
  const int bm = blockIdx.y * 128;
  const int bn = blockIdx.x * 128;

  const int drow0 = w * 16 + (lane >> 2);
  const int drow1 = drow0 + 64;
  const int slot = lane & 3;
  const int ch0 = slot ^ ((drow0 >> 1) & 3);
  const int ch1 = slot ^ ((drow1 >> 1) & 3);
  const short* gA0 = &A[(size_t)(bm + drow0) * K + ch0 * 8];
  const short* gA1 = &A[(size_t)(bm + drow1) * K + ch1 * 8];
  const short* gB0 = &B[(size_t)(bn + drow0) * K + ch0 * 8];
  const short* gB1 = &B[(size_t)(bn + drow1) * K + ch1 * 8];
  const int dA0 = (w * 16) * 32, dA1 = (64 + w * 16) * 32;

  const int wm = (w & 1) * 64, wn = (w >> 1) * 64;
  int offA[4], offB[4];
#pragma unroll
  for (int i = 0; i < 4; ++i) {
    int R = wm + i * 16 + l16;
    offA[i] = R * 32 + (quad ^ ((R >> 1) & 3)) * 8;
    int Rb = wn + i * 16 + l16;
    offB[i] = Rb * 32 + (quad ^ ((Rb >> 1) & 3)) * 8;
  }

  f32x4 acc[4][4];
#pragma unroll
  for (int i = 0; i < 4; ++i)
#pragma unroll
    for (int j = 0; j < 4; ++j)
#pragma unroll
      for (int e = 0; e < 4; ++e) acc[i][j][e] = 0.f;

  const int T = K / 32;
  dma16(gA0, &As[0][dA0]);
  dma16(gA1, &As[0][dA1]);
  dma16(gB0, &Bs[0][dA0]);
  dma16(gB1, &Bs[0][dA1]);
  __syncthreads();

  for (int t = 0; t < T; ++t) {
    const int cur = t & 1, nxt = cur ^ 1;
    if (t + 1 < T) {
      const int ko = (t + 1) * 32;
      dma16(gA0 + ko, &As[nxt][dA0]);
      dma16(gA1 + ko, &As[nxt][dA1]);
      dma16(gB0 + ko, &Bs[nxt][dA0]);
      dma16(gB1 + ko, &Bs[nxt][dA1]);
    }
    short8 af[4], bf[4];
#pragma unroll
    for (int i = 0; i < 4; ++i) af[i] = *(const short8*)&As[cur][offA[i]];
#pragma unroll
    for (int j = 0; j < 4; ++j) bf[j] = *(const short8*)&Bs[cur][offB[j]];
#pragma unroll
    for (int i = 0; i < 4; ++i)
#pragma unroll
      for (int j = 0; j < 4; ++j)
        acc[i][j] = __builtin_amdgcn_mfma_f32_16x16x32_bf16(af[i], bf[j], acc[i][j], 0, 0, 0);
    __syncthreads();
  }

#pragma unroll
  for (int i = 0; i < 4; ++i) {
#pragma unroll
    for (int j = 0; j < 4; ++j) {
      const int col = bn + wn + j * 16 + l16;
      const float bv = bias[col];
      const int row0 = bm + wm + i * 16 + quad * 4;
#pragma unroll
      for (int e = 0; e < 4; ++e)
        C[(size_t)(row0 + e) * N + col] = acc[i][j][e] + bv;
    }
  }
}

// ---------------------------------------------------------------------------
// Merged RoPE kernel (one launch): blocks [0,8192) do Q (rope+pack,
// prescaled by log2e/8 -> Qb[h][s][64]); blocks [8192,8448) do K->Kb and
// V->Vt (transposed). All frequencies from freqTab (no device pow).
// ---------------------------------------------------------------------------
#define QSCALE 0.18033688011112042f   // (1/8) * log2(e)

__global__ __launch_bounds__(256) void rope_all(
    const float* __restrict__ Qf, const float* __restrict__ KVf,
    const float* __restrict__ tab, short* __restrict__ Qb,
    short* __restrict__ Kb, short* __restrict__ Vt) {
  __shared__ short Vtile[64][72];
  const int tid = threadIdx.x;

  if (blockIdx.x < 8192) {
    // ---- Q part: one thread per rotation pair ----
    const int g = blockIdx.x * 256 + tid;
    const int s = g >> 10;
    const int rem = g & 1023;
    const int h = rem >> 5, j = rem & 31;
    const float theta = (float)s * tab[j];
    float sn, cs;
    fast_sincos(theta, sn, cs);
    const float* p = &Qf[(size_t)s * D_MODEL + h * 64 + 2 * j];
    const float x1 = p[0], x2 = p[1];
    short2 o;
    o.x = bf16_rne((x1 * cs - x2 * sn) * QSCALE);
    o.y = bf16_rne((x1 * sn + x2 * cs) * QSCALE);
    *(short2*)&Qb[((size_t)h * S_LEN + s) * 64 + 2 * j] = o;
    return;
  }

  // ---- KV part ----
  const int bb = blockIdx.x - 8192;
  const int st = bb & 31, kvh = bb >> 5;

  {
    const int sr = tid >> 2, sc = (tid & 3) * 16;
    const int s = st * 64 + sr;
    const float* kg = &KVf[(size_t)s * 1024 + kvh * 64 + sc];
    short tmp[16];
#pragma unroll
    for (int i = 0; i < 8; ++i) {
      const int j = (sc >> 1) + i;
      const float theta = (float)s * tab[j];
      float sn, cs;
      fast_sincos(theta, sn, cs);
      const float x1 = kg[2 * i], x2 = kg[2 * i + 1];
      tmp[2 * i]     = bf16_rne(x1 * cs - x2 * sn);
      tmp[2 * i + 1] = bf16_rne(x1 * sn + x2 * cs);
    }
    short* out = &Kb[((size_t)kvh * S_LEN + s) * 64 + sc];
    *(short8*)&out[0] = *(short8*)&tmp[0];
    *(short8*)&out[8] = *(short8*)&tmp[8];
  }

  {
    const int sr = tid >> 2, sc = (tid & 3) * 16;
    const float* vg = &KVf[(size_t)(st * 64 + sr) * 1024 + 512 + kvh * 64 + sc];
    short tmp[16];
#pragma unroll
    for (int c = 0; c < 16; c += 4) {
      float4 v = *(const float4*)&vg[c];
      tmp[c + 0] = bf16_rne(v.x);
      tmp[c + 1] = bf16_rne(v.y);
      tmp[c + 2] = bf16_rne(v.z);
      tmp[c + 3] = bf16_rne(v.w);
    }
    *(short8*)&Vtile[sr][sc]     = *(short8*)&tmp[0];
    *(short8*)&Vtile[sr][sc + 8] = *(short8*)&tmp[8];
  }
  __syncthreads();
  {
    const int d = tid & 63, kchunk = tid >> 6;
    short tmp[16];
#pragma unroll
    for (int k = 0; k < 16; ++k) tmp[k] = Vtile[kchunk * 16 + k][d];
    short* out = &Vt[((size_t)kvh * 64 + d) * S_LEN + st * 64 + kchunk * 16];
    *(short8*)&out[0] = *(short8*)&tmp[0];
    *(short8*)&out[8] = *(short8*)&tmp[8];
  }
}

// ---------------------------------------------------------------------------
// MFMA flash attention v8 (unchanged from R10): K/V LDS DMA dbuf, one
// barrier/tile, fixed-reference exp2 softmax, l via ones-MFMA, Ps stride-64
// XOR-swizzled. LDS = 40960 B.
// ---------------------------------------------------------------------------
__global__ __launch_bounds__(256, 4) void flash8(
    const short* __restrict__ Qb, const short* __restrict__ Kb,
    const short* __restrict__ Vt, short* __restrict__ Oh) {
  const int qt = blockIdx.x, h = blockIdx.y;
  const int kvh = h >> 2;
  const int tid = threadIdx.x;
  const int w = tid >> 6, lane = tid & 63;
  const int l16 = lane & 15, quad = lane >> 4;

  __shared__ short Ks[2][64 * 64];
  __shared__ short Vs[2][64 * 64];
  __shared__ short Ps[64 * 64];

  const short* Kh = Kb + (size_t)kvh * S_LEN * 64;
  const short* Vh = Vt + (size_t)kvh * 64 * S_LEN;
  const int qr = qt * 64 + w * 16 + l16;

  short8 qf0 = *(const short8*)&Qb[((size_t)h * S_LEN + qr) * 64 + quad * 8];
  short8 qf1 = *(const short8*)&Qb[((size_t)h * S_LEN + qr) * 64 + 32 + quad * 8];

  short8 ones;
#pragma unroll
  for (int e = 0; e < 8; ++e) ones[e] = (short)0x3F80;   // bf16 1.0

  const int drow = lane >> 3;
  const int ch = (lane & 7) ^ drow;
  const short* gK = &Kh[(size_t)(w * 16 + drow) * 64 + ch * 8];
  const short* gV = &Vh[(size_t)(w * 16 + drow) * S_LEN + ch * 8];

  const int sl0 = quad ^ (l16 & 7);
  int offT[4][2];
#pragma unroll
  for (int m = 0; m < 4; ++m) {
    offT[m][0] = (m * 16 + l16) * 64 + sl0 * 8;
    offT[m][1] = (m * 16 + l16) * 64 + (sl0 ^ 4) * 8;
  }

  const int prow = (w * 16 + l16) * 64;
  const int pswz = (l16 & 7) << 1;
  int pwr[4];
#pragma unroll
  for (int m = 0; m < 4; ++m) pwr[m] = prow + ((4 * m + quad) ^ pswz) * 4;
  const int prd0 = prow + ((2 * quad) ^ pswz) * 4;
  const int prd1 = prow + ((8 + 2 * quad) ^ pswz) * 4;

  f32x4 accl;
#pragma unroll
  for (int e = 0; e < 4; ++e) accl[e] = 0.f;
  f32x4 acco[4];
#pragma unroll
  for (int m = 0; m < 4; ++m)
#pragma unroll
    for (int e = 0; e < 4; ++e) acco[m][e] = 0.f;

  dma16(gK,               &Ks[0][(w * 16) * 64]);
  dma16(gK + 8 * 64,      &Ks[0][(w * 16 + 8) * 64]);
  dma16(gV,               &Vs[0][(w * 16) * 64]);
  dma16(gV + 8 * S_LEN,   &Vs[0][(w * 16 + 8) * 64]);
  __syncthreads();

  for (int t = 0; t < 32; ++t) {
    const int cur = t & 1, nxt = cur ^ 1;
    if (t + 1 < 32) {
      const short* gKn = gK + (t + 1) * 4096;
      const short* gVn = gV + (t + 1) * 64;
      dma16(gKn,             &Ks[nxt][(w * 16) * 64]);
      dma16(gKn + 8 * 64,    &Ks[nxt][(w * 16 + 8) * 64]);
      dma16(gVn,             &Vs[nxt][(w * 16) * 64]);
      dma16(gVn + 8 * S_LEN, &Vs[nxt][(w * 16 + 8) * 64]);
    }

    const short* kc = Ks[cur];
    f32x4 accs[4];
#pragma unroll
    for (int m = 0; m < 4; ++m)
#pragma unroll
      for (int e = 0; e < 4; ++e) accs[m][e] = 0.f;
#pragma unroll
    for (int m = 0; m < 4; ++m) {
      short8 k0 = *(const short8*)&kc[offT[m][0]];
      short8 k1 = *(const short8*)&kc[offT[m][1]];
      accs[m] = __builtin_amdgcn_mfma_f32_16x16x32_bf16(k0, qf0, accs[m], 0, 0, 0);
      accs[m] = __builtin_amdgcn_mfma_f32_16x16x32_bf16(k1, qf1, accs[m], 0, 0, 0);
    }

#pragma unroll
    for (int m = 0; m < 4; ++m) {
      float p0 = exp2f(accs[m][0]);
      float p1 = exp2f(accs[m][1]);
      float p2 = exp2f(accs[m][2]);
      float p3 = exp2f(accs[m][3]);
      unsigned u01 = __builtin_amdgcn_perm(__float_as_uint(p1), __float_as_uint(p0), 0x07060302u);
      unsigned u23 = __builtin_amdgcn_perm(__float_as_uint(p3), __float_as_uint(p2), 0x07060302u);
      *(uint2*)&Ps[pwr[m]] = make_uint2(u01, u23);
    }

    short8 pf0 = *(const short8*)&Ps[prd0];
    short8 pf1 = *(const short8*)&Ps[prd1];
    accl = __builtin_amdgcn_mfma_f32_16x16x32_bf16(ones, pf0, accl, 0, 0, 0);
    accl = __builtin_amdgcn_mfma_f32_16x16x32_bf16(ones, pf1, accl, 0, 0, 0);
    const short* vc = Vs[cur];
#pragma unroll
    for (int m = 0; m < 4; ++m) {
      short8 v0 = *(const short8*)&vc[offT[m][0]];
      short8 v1 = *(const short8*)&vc[offT[m][1]];
      acco[m] = __builtin_amdgcn_mfma_f32_16x16x32_bf16(v0, pf0, acco[m], 0, 0, 0);
      acco[m] = __builtin_amdgcn_mfma_f32_16x16x32_bf16(v1, pf1, acco[m], 0, 0, 0);
    }

    __syncthreads();
  }

  const float inv = 1.f / accl[0];
#pragma unroll
  for (int m = 0; m < 4; ++m) {
    short4 h4;
    h4.x = bf16_rne(acco[m][0] * inv);
    h4.y = bf16_rne(acco[m][1] * inv);
    h4.z = bf16_rne(acco[m][2] * inv);
    h4.w = bf16_rne(acco[m][3] * inv);
    const size_t base = (size_t)qr * D_MODEL + h * 64 + m * 16 + quad * 4;
    *(short4*)&Oh[base] = h4;
  }
}

// ---------------------------------------------------------------------------
extern "C" void kernel_launch(void* const* d_in, const int* in_sizes, int n_in,
                              void* d_out, int out_size, void* d_ws, size_t ws_size,
                              hipStream_t stream) {
  const float* x     = (const float*)d_in[0];
  const float* W_q   = (const float*)d_in[1];
  const float* b_q   = (const float*)d_in[2];
  const float* W_kv  = (const float*)d_in[3];
  const float* b_kv  = (const float*)d_in[4];
  const float* W_out = (const float*)d_in[5];
  const float* b_out = (const float*)d_in[6];
  float* out = (float*)d_out;

  char* ws = (char*)d_ws;                        // ~64 MB used
  float* Qbuf  = (float*)(ws);                   // 16 MB fp32 [2048,2048]
  float* KVbuf = (float*)(ws + (16u << 20));     //  8 MB fp32 [2048,1024]
  short* xh    = (short*)(ws + (24u << 20));     //  8 MB
  short* Wqh   = (short*)(ws + (32u << 20));     //  8 MB
  short* Wkvh  = (short*)(ws + (40u << 20));     //  4 MB
  short* Woh   = (short*)(ws + (44u << 20));     //  8 MB
  short* Qb    = (short*)(ws + (52u << 20));     //  8 MB bf16 [32][2048][64]
  short* Kb    = (short*)(ws + (60u << 20));     //  2 MB bf16 [8][2048][64]
  short* Vtb   = (short*)(ws + (62u << 20));     //  2 MB bf16 [8][64][2048]
  float* freqTab = (float*)(ws + (64u << 20));   //  128 B
  short* Ath   = xh;   // x dead after gemm_nt1_dual

  // fused conversion + freq-table launch
  cvt_all<<<7168, 256, 0, stream>>>(x, xh, W_q, Wqh, W_kv, Wkvh, W_out, Woh,
                                    freqTab);

  // Q+KV projection: BM=128 BN=64 -> 768 blocks = 3.0/CU
  gemm_nt1_dual<<<dim3(3072 / 64, 2048 / 128), 256, 0, stream>>>(
      xh, Wqh, Wkvh, b_q, b_kv, Qbuf, KVbuf, 2048, 1024, 2048);

  // merged RoPE (Q pack + K pack + V transpose) in one launch
  rope_all<<<8192 + 256, 256, 0, stream>>>(Qbuf, KVbuf, freqTab, Qb, Kb, Vtb);

  flash8<<<dim3(S_LEN / 64, Q_HEADS), 256, 0, stream>>>(Qb, Kb, Vtb, Ath);

  gemm_nt1_big<<<dim3(2048 / 128, 2048 / 128), 256, 0, stream>>>(
      Ath, Woh, b_out, out, 2048, 2048);
}

// Round 12
// 261.666 us; speedup vs baseline: 1.2909x; 1.0098x over previous
//
#include <hip/hip_runtime.h>
#include <hip/hip_bf16.h>
#include <math.h>

#define S_LEN 2048
#define D_MODEL 2048
#define Q_HEADS 32
#define KV_HEADS 8

typedef __attribute__((ext_vector_type(8))) short short8;   // 8 bf16 = 4 VGPRs
typedef __attribute__((ext_vector_type(4))) float f32x4;

// ---------------------------------------------------------------------------
// helpers
// ---------------------------------------------------------------------------
__device__ __forceinline__ short bf16_rne(float f) {
  unsigned u = __float_as_uint(f);
  unsigned r = (u + 0x7FFFu + ((u >> 16) & 1u)) >> 16;
  return (short)r;
}
// async global->LDS DMA, 16B per lane; lds dest = wave-uniform base + lane*16
__device__ __forceinline__ void dma16(const short* g, short* l) {
  __builtin_amdgcn_global_load_lds(
      (const __attribute__((address_space(1))) void*)g,
      (__attribute__((address_space(3))) void*)l, 16, 0, 0);
}
// hw trig on fp32 theta (radians) via fp64 range reduction to revolutions
__device__ __forceinline__ void fast_sincos(float theta, float& sn, float& cs) {
  double rev = (double)theta * 0.15915494309189535;  // theta / 2pi
  float fr = (float)(rev - floor(rev));
  sn = __builtin_amdgcn_sinf(fr);
  cs = __builtin_amdgcn_cosf(fr);
}
__device__ __forceinline__ void cvt8(const float* src, short* dst, int i) {
  float4 a = *(const float4*)&src[i];
  float4 b = *(const float4*)&src[i + 4];
  short8 h;
  h[0] = bf16_rne(a.x); h[1] = bf16_rne(a.y);
  h[2] = bf16_rne(a.z); h[3] = bf16_rne(a.w);
  h[4] = bf16_rne(b.x); h[5] = bf16_rne(b.y);
  h[6] = bf16_rne(b.z); h[7] = bf16_rne(b.w);
  *(short8*)&dst[i] = h;
}

// ---------------------------------------------------------------------------
// Fused fp32->bf16 conversion of x, W_q, W_kv, W_out in ONE launch.
// Block 0 additionally computes the 32 RoPE frequencies (double pow, rounded
// once to fp32 - bit-identical to per-thread pow).
// ---------------------------------------------------------------------------
#define NM (2048 * 2048)
#define NKV (1024 * 2048)

__global__ __launch_bounds__(256) void cvt_all(
    const float* __restrict__ x,    short* __restrict__ xh,
    const float* __restrict__ wq,   short* __restrict__ wqh,
    const float* __restrict__ wkv,  short* __restrict__ wkvh,
    const float* __restrict__ wo,   short* __restrict__ woh,
    float* __restrict__ freqTab) {
  if (blockIdx.x == 0 && threadIdx.x < 32) {
    const double e = (2.0 * threadIdx.x) / 64.0;
    freqTab[threadIdx.x] = (float)pow(10000.0, -e);
  }
  int i = (blockIdx.x * 256 + threadIdx.x) * 8;
  if (i < NM) { cvt8(x, xh, i); return; }
  i -= NM;
  if (i < NM) { cvt8(wq, wqh, i); return; }
  i -= NM;
  if (i < NKV) { cvt8(wkv, wkvh, i); return; }
  i -= NKV;
  cvt8(wo, woh, i);
}

// ---------------------------------------------------------------------------
// QKV projection GEMM with FUSED RoPE + pack epilogue. BM=128 BN=64,
// 768 blocks = 3.0/CU, DMA dbuf staging (unchanged loop from R11 dual).
// Epilogue (C-layout: lane = one col, regs = 4 consecutive rows = seq pos):
//   - RoPE pair partner (col^1) is lane^1, same rows -> one __shfl_xor + 2 FMA
//   - Q blocks: rope, *QSCALE, bf16 -> Qrm[s][2048] row-major
//   - K blocks: rope, bf16 -> Krm[s][512] row-major
//   - V blocks: bf16 -> Vt[d][s] (transpose is FREE: 4 consecutive s = short4)
// Numerics bit-identical to the separate rope kernel (same fp32 acc + bias).
// ---------------------------------------------------------------------------
#define QSCALE 0.18033688011112042f   // (1/8) * log2(e)

__global__ __launch_bounds__(256) void gemm_qkv_rope(
    const short* __restrict__ Ah,
    const short* __restrict__ Bq, const short* __restrict__ Bkv,
    const float* __restrict__ bq, const float* __restrict__ bkv,
    const float* __restrict__ tab,
    short* __restrict__ Qrm, short* __restrict__ Krm,
    short* __restrict__ Vt) {
  const int Nq = 2048, K = 2048;
  __shared__ short As[2][128 * 32];
  __shared__ short Bs[2][64 * 32];
  const int tid = threadIdx.x;
  const int w = tid >> 6, lane = tid & 63;
  const int l16 = lane & 15, quad = lane >> 4;
  const int bm = blockIdx.y * 128;
  const int bnG = blockIdx.x * 64;

  const short* Bsrc; const float* bias; int bn;
  if (bnG < Nq) { Bsrc = Bq;  bias = bq;  bn = bnG; }
  else          { Bsrc = Bkv; bias = bkv; bn = bnG - Nq; }
  const int mode = (bnG < Nq) ? 0 : ((bnG < Nq + 512) ? 1 : 2);

  const int drow0 = w * 16 + (lane >> 2);
  const int drow1 = drow0 + 64;
  const int slot = lane & 3;
  const int ch0 = slot ^ ((drow0 >> 1) & 3);
  const int ch1 = slot ^ ((drow1 >> 1) & 3);
  const size_t a0 = (size_t)(bm + drow0) * K + ch0 * 8;
  const size_t a1 = (size_t)(bm + drow1) * K + ch1 * 8;
  const size_t b0 = (size_t)(bn + drow0) * K + ch0 * 8;
  const int dA0 = (w * 16) * 32, dA1 = (64 + w * 16) * 32;

  const int wm = (w & 1) * 64, wn = (w >> 1) * 32;
  int offA[4], offB[2];
#pragma unroll
  for (int i = 0; i < 4; ++i) {
    int R = wm + i * 16 + l16;
    offA[i] = R * 32 + (quad ^ ((R >> 1) & 3)) * 8;
  }
#pragma unroll
  for (int j = 0; j < 2; ++j) {
    int R = wn + j * 16 + l16;
    offB[j] = R * 32 + (quad ^ ((R >> 1) & 3)) * 8;
  }

  f32x4 acc[4][2];
#pragma unroll
  for (int i = 0; i < 4; ++i)
#pragma unroll
    for (int j = 0; j < 2; ++j)
#pragma unroll
      for (int e = 0; e < 4; ++e) acc[i][j][e] = 0.f;

  const int T = K / 32;
  dma16(Ah + a0, &As[0][dA0]);
  dma16(Ah + a1, &As[0][dA1]);
  dma16(Bsrc + b0, &Bs[0][dA0]);
  __syncthreads();

  for (int t = 0; t < T; ++t) {
    const int cur = t & 1, nxt = cur ^ 1;
    if (t + 1 < T) {
      const int ko = (t + 1) * 32;
      dma16(Ah + a0 + ko, &As[nxt][dA0]);
      dma16(Ah + a1 + ko, &As[nxt][dA1]);
      dma16(Bsrc + b0 + ko, &Bs[nxt][dA0]);
    }
    short8 af[4], bf[2];
#pragma unroll
    for (int i = 0; i < 4; ++i) af[i] = *(const short8*)&As[cur][offA[i]];
#pragma unroll
    for (int j = 0; j < 2; ++j) bf[j] = *(const short8*)&Bs[cur][offB[j]];
#pragma unroll
    for (int i = 0; i < 4; ++i)
#pragma unroll
      for (int j = 0; j < 2; ++j)
        acc[i][j] = __builtin_amdgcn_mfma_f32_16x16x32_bf16(af[i], bf[j], acc[i][j], 0, 0, 0);
    __syncthreads();
  }

  // ---- fused epilogue ----
#pragma unroll
  for (int i = 0; i < 4; ++i) {
    const int row0 = bm + wm + i * 16 + quad * 4;
#pragma unroll
    for (int j = 0; j < 2; ++j) {
      const int col = bn + wn + j * 16 + l16;
      const float bv = bias[col];
      if (mode == 2) {
        // V: plain bf16, transposed store (4 consecutive seq-pos = short4)
        const int d = col - 512;          // = kvh*64 + dd
        short4 sv;
        sv.x = bf16_rne(acc[i][j][0] + bv);
        sv.y = bf16_rne(acc[i][j][1] + bv);
        sv.z = bf16_rne(acc[i][j][2] + bv);
        sv.w = bf16_rne(acc[i][j][3] + bv);
        *(short4*)&Vt[(size_t)d * S_LEN + row0] = sv;
      } else {
        // Q/K: RoPE via lane^1 partner exchange
        const float fr = tab[(col & 63) >> 1];
        const float sgn = (col & 1) ? 1.f : -1.f;
#pragma unroll
        for (int e = 0; e < 4; ++e) {
          float v = acc[i][j][e] + bv;
          float other = __shfl_xor(v, 1);
          float sn, cs;
          fast_sincos((float)(row0 + e) * fr, sn, cs);
          const float o = v * cs + sgn * other * sn;
          if (mode == 0)
            Qrm[(size_t)(row0 + e) * D_MODEL + col] = bf16_rne(o * QSCALE);
          else
            Krm[(size_t)(row0 + e) * 512 + col] = bf16_rne(o);
        }
      }
    }
  }
}

// ---------------------------------------------------------------------------
// Single-output bf16 NT GEMM, BM=BN=128 (out-projection) - unchanged.
// ---------------------------------------------------------------------------
__global__ __launch_bounds__(256) void gemm_nt1_big(
    const short* __restrict__ A, const short* __restrict__ B,
    const float* __restrict__ bias, float* __restrict__ C,
    int N, int K) {
  __shared__ short As[2][128 * 32];
  __shared__ short Bs[2][128 * 32];
  const int tid = threadIdx.x;
  const int w = tid >> 6, lane = tid & 63;
  const int l16 = lane & 15, quad = lane >> 4;
  const int bm = blockIdx.y * 128;
  const int bn = blockIdx.x * 128;

  const int drow0 = w * 16 + (lane >> 2);
  const int drow1 = drow0 + 64;
  const int slot = lane & 3;
  const int ch0 = slot ^ ((drow0 >> 1) & 3);
  const int ch1 = slot ^ ((drow1 >> 1) & 3);
  const short* gA0 = &A[(size_t)(bm + drow0) * K + ch0 * 8];
  const short* gA1 = &A[(size_t)(bm + drow1) * K + ch1 * 8];
  const short* gB0 = &B[(size_t)(bn + drow0) * K + ch0 * 8];
  const short* gB1 = &B[(size_t)(bn + drow1) * K + ch1 * 8];
  const int dA0 = (w * 16) * 32, dA1 = (64 + w * 16) * 32;

  const int wm = (w & 1) * 64, wn = (w >> 1) * 64;
  int offA[4], offB[4];
#pragma unroll
  for (int i = 0; i < 4; ++i) {
    int R = wm + i * 16 + l16;
    offA[i] = R * 32 + (quad ^ ((R >> 1) & 3)) * 8;
    int Rb = wn + i * 16 + l16;
    offB[i] = Rb * 32 + (quad ^ ((Rb >> 1) & 3)) * 8;
  }

  f32x4 acc[4][4];
#pragma unroll
  for (int i = 0; i < 4; ++i)
#pragma unroll
    for (int j = 0; j < 4; ++j)
#pragma unroll
      for (int e = 0; e < 4; ++e) acc[i][j][e] = 0.f;

  const int T = K / 32;
  dma16(gA0, &As[0][dA0]);
  dma16(gA1, &As[0][dA1]);
  dma16(gB0, &Bs[0][dA0]);
  dma16(gB1, &Bs[0][dA1]);
  __syncthreads();

  for (int t = 0; t < T; ++t) {
    const int cur = t & 1, nxt = cur ^ 1;
    if (t + 1 < T) {
      const int ko = (t + 1) * 32;
      dma16(gA0 + ko, &As[nxt][dA0]);
      dma16(gA1 + ko, &As[nxt][dA1]);
      dma16(gB0 + ko, &Bs[nxt][dA0]);
      dma16(gB1 + ko, &Bs[nxt][dA1]);
    }
    short8 af[4], bf[4];
#pragma unroll
    for (int i = 0; i < 4; ++i) af[i] = *(const short8*)&As[cur][offA[i]];
#pragma unroll
    for (int j = 0; j < 4; ++j) bf[j] = *(const short8*)&Bs[cur][offB[j]];
#pragma unroll
    for (int i = 0; i < 4; ++i)
#pragma unroll
      for (int j = 0; j < 4; ++j)
        acc[i][j] = __builtin_amdgcn_mfma_f32_16x16x32_bf16(af[i], bf[j], acc[i][j], 0, 0, 0);
    __syncthreads();
  }

#pragma unroll
  for (int i = 0; i < 4; ++i) {
#pragma unroll
    for (int j = 0; j < 4; ++j) {
      const int col = bn + wn + j * 16 + l16;
      const float bv = bias[col];
      const int row0 = bm + wm + i * 16 + quad * 4;
#pragma unroll
      for (int e = 0; e < 4; ++e)
        C[(size_t)(row0 + e) * N + col] = acc[i][j][e] + bv;
    }
  }
}

// ---------------------------------------------------------------------------
// MFMA flash attention v8 (R10 structure), inputs re-addressed:
// Q row-major bf16 [s][2048] (pre-roped, pre-scaled), K row-major [s][512]
// (per-row head slice contiguous -> DMA row stride 512), V pre-transposed
// [kvh][64][S]. LDS = 40960 B -> 4 blocks/CU.
// ---------------------------------------------------------------------------
__global__ __launch_bounds__(256, 4) void flash8(
    const short* __restrict__ Qrm, const short* __restrict__ Krm,
    const short* __restrict__ Vt, short* __restrict__ Oh) {
  const int qt = blockIdx.x, h = blockIdx.y;
  const int kvh = h >> 2;
  const int tid = threadIdx.x;
  const int w = tid >> 6, lane = tid & 63;
  const int l16 = lane & 15, quad = lane >> 4;

  __shared__ short Ks[2][64 * 64];
  __shared__ short Vs[2][64 * 64];
  __shared__ short Ps[64 * 64];

  const short* Vh = Vt + (size_t)kvh * 64 * S_LEN;
  const int qr = qt * 64 + w * 16 + l16;

  short8 qf0 = *(const short8*)&Qrm[(size_t)qr * D_MODEL + h * 64 + quad * 8];
  short8 qf1 = *(const short8*)&Qrm[(size_t)qr * D_MODEL + h * 64 + 32 + quad * 8];

  short8 ones;
#pragma unroll
  for (int e = 0; e < 8; ++e) ones[e] = (short)0x3F80;   // bf16 1.0

  const int drow = lane >> 3;
  const int ch = (lane & 7) ^ drow;
  const short* gK = &Krm[(size_t)(w * 16 + drow) * 512 + kvh * 64 + ch * 8];
  const short* gV = &Vh[(size_t)(w * 16 + drow) * S_LEN + ch * 8];

  const int sl0 = quad ^ (l16 & 7);
  int offT[4][2];
#pragma unroll
  for (int m = 0; m < 4; ++m) {
    offT[m][0] = (m * 16 + l16) * 64 + sl0 * 8;
    offT[m][1] = (m * 16 + l16) * 64 + (sl0 ^ 4) * 8;
  }

  const int prow = (w * 16 + l16) * 64;
  const int pswz = (l16 & 7) << 1;
  int pwr[4];
#pragma unroll
  for (int m = 0; m < 4; ++m) pwr[m] = prow + ((4 * m + quad) ^ pswz) * 4;
  const int prd0 = prow + ((2 * quad) ^ pswz) * 4;
  const int prd1 = prow + ((8 + 2 * quad) ^ pswz) * 4;

  f32x4 accl;
#pragma unroll
  for (int e = 0; e < 4; ++e) accl[e] = 0.f;
  f32x4 acco[4];
#pragma unroll
  for (int m = 0; m < 4; ++m)
#pragma unroll
    for (int e = 0; e < 4; ++e) acco[m][e] = 0.f;

  dma16(gK,               &Ks[0][(w * 16) * 64]);
  dma16(gK + 8 * 512,     &Ks[0][(w * 16 + 8) * 64]);
  dma16(gV,               &Vs[0][(w * 16) * 64]);
  dma16(gV + 8 * S_LEN,   &Vs[0][(w * 16 + 8) * 64]);
  __syncthreads();

  for (int t = 0; t < 32; ++t) {
    const int cur = t & 1, nxt = cur ^ 1;
    if (t + 1 < 32) {
      const short* gKn = gK + (size_t)(t + 1) * 64 * 512;
      const short* gVn = gV + (t + 1) * 64;
      dma16(gKn,             &Ks[nxt][(w * 16) * 64]);
      dma16(gKn + 8 * 512,   &Ks[nxt][(w * 16 + 8) * 64]);
      dma16(gVn,             &Vs[nxt][(w * 16) * 64]);
      dma16(gVn + 8 * S_LEN, &Vs[nxt][(w * 16 + 8) * 64]);
    }

    const short* kc = Ks[cur];
    f32x4 accs[4];
#pragma unroll
    for (int m = 0; m < 4; ++m)
#pragma unroll
      for (int e = 0; e < 4; ++e) accs[m][e] = 0.f;
#pragma unroll
    for (int m = 0; m < 4; ++m) {
      short8 k0 = *(const short8*)&kc[offT[m][0]];
      short8 k1 = *(const short8*)&kc[offT[m][1]];
      accs[m] = __builtin_amdgcn_mfma_f32_16x16x32_bf16(k0, qf0, accs[m], 0, 0, 0);
      accs[m] = __builtin_amdgcn_mfma_f32_16x16x32_bf16(k1, qf1, accs[m], 0, 0, 0);
    }

#pragma unroll
    for (int m = 0; m < 4; ++m) {
      float p0 = exp2f(accs[m][0]);
      float p1 = exp2f(accs[m][1]);
      float p2 = exp2f(accs[m][2]);
      float p3 = exp2f(accs[m][3]);
      unsigned u01 = __builtin_amdgcn_perm(__float_as_uint(p1), __float_as_uint(p0), 0x07060302u);
      unsigned u23 = __builtin_amdgcn_perm(__float_as_uint(p3), __float_as_uint(p2), 0x07060302u);
      *(uint2*)&Ps[pwr[m]] = make_uint2(u01, u23);
    }

    short8 pf0 = *(const short8*)&Ps[prd0];
    short8 pf1 = *(const short8*)&Ps[prd1];
    accl = __builtin_amdgcn_mfma_f32_16x16x32_bf16(ones, pf0, accl, 0, 0, 0);
    accl = __builtin_amdgcn_mfma_f32_16x16x32_bf16(ones, pf1, accl, 0, 0, 0);
    const short* vc = Vs[cur];
#pragma unroll
    for (int m = 0; m < 4; ++m) {
      short8 v0 = *(const short8*)&vc[offT[m][0]];
      short8 v1 = *(const short8*)&vc[offT[m][1]];
      acco[m] = __builtin_amdgcn_mfma_f32_16x16x32_bf16(v0, pf0, acco[m], 0, 0, 0);
      acco[m] = __builtin_amdgcn_mfma_f32_16x16x32_bf16(v1, pf1, acco[m], 0, 0, 0);
    }

    __syncthreads();
  }

  const float inv = 1.f / accl[0];
#pragma unroll
  for (int m = 0; m < 4; ++m) {
    short4 h4;
    h4.x = bf16_rne(acco[m][0] * inv);
    h4.y = bf16_rne(acco[m][1] * inv);
    h4.z = bf16_rne(acco[m][2] * inv);
    h4.w = bf16_rne(acco[m][3] * inv);
    const size_t base = (size_t)qr * D_MODEL + h * 64 + m * 16 + quad * 4;
    *(short4*)&Oh[base] = h4;
  }
}

// ---------------------------------------------------------------------------
extern "C" void kernel_launch(void* const* d_in, const int* in_sizes, int n_in,
                              void* d_out, int out_size, void* d_ws, size_t ws_size,
                              hipStream_t stream) {
  const float* x     = (const float*)d_in[0];
  const float* W_q   = (const float*)d_in[1];
  const float* b_q   = (const float*)d_in[2];
  const float* W_kv  = (const float*)d_in[3];
  const float* b_kv  = (const float*)d_in[4];
  const float* W_out = (const float*)d_in[5];
  const float* b_out = (const float*)d_in[6];
  float* out = (float*)d_out;

  char* ws = (char*)d_ws;                        // ~41 MB used
  short* xh    = (short*)(ws);                   //  8 MB
  short* Wqh   = (short*)(ws + (8u << 20));      //  8 MB
  short* Wkvh  = (short*)(ws + (16u << 20));     //  4 MB
  short* Woh   = (short*)(ws + (20u << 20));     //  8 MB
  short* Qrm   = (short*)(ws + (28u << 20));     //  8 MB bf16 [2048][2048]
  short* Krm   = (short*)(ws + (36u << 20));     //  2 MB bf16 [2048][512]
  short* Vtb   = (short*)(ws + (38u << 20));     //  2 MB bf16 [8][64][2048]
  float* freqTab = (float*)(ws + (40u << 20));   //  128 B
  short* Ath   = xh;   // x dead after gemm_qkv_rope

  // fused conversion + freq-table launch
  cvt_all<<<7168, 256, 0, stream>>>(x, xh, W_q, Wqh, W_kv, Wkvh, W_out, Woh,
                                    freqTab);

  // QKV projection with fused RoPE/pack/transpose epilogue (768 blocks)
  gemm_qkv_rope<<<dim3(3072 / 64, 2048 / 128), 256, 0, stream>>>(
      xh, Wqh, Wkvh, b_q, b_kv, freqTab, Qrm, Krm, Vtb);

  flash8<<<dim3(S_LEN / 64, Q_HEADS), 256, 0, stream>>>(Qrm, Krm, Vtb, Ath);

  gemm_nt1_big<<<dim3(2048 / 128, 2048 / 128), 256, 0, stream>>>(
      Ath, Woh, b_out, out, 2048, 2048);
}

// Round 13
// 254.253 us; speedup vs baseline: 1.3285x; 1.0292x over previous
//
#include <hip/hip_runtime.h>
#include <hip/hip_bf16.h>
#include <math.h>

#define S_LEN 2048
#define D_MODEL 2048
#define Q_HEADS 32
#define KV_HEADS 8

typedef __attribute__((ext_vector_type(8))) short short8;   // 8 bf16 = 4 VGPRs
typedef __attribute__((ext_vector_type(4))) float f32x4;

// ---------------------------------------------------------------------------
// helpers
// ---------------------------------------------------------------------------
__device__ __forceinline__ short bf16_rne(float f) {
  unsigned u = __float_as_uint(f);
  unsigned r = (u + 0x7FFFu + ((u >> 16) & 1u)) >> 16;
  return (short)r;
}
// async global->LDS DMA, 16B per lane; lds dest = wave-uniform base + lane*16
__device__ __forceinline__ void dma16(const short* g, short* l) {
  __builtin_amdgcn_global_load_lds(
      (const __attribute__((address_space(1))) void*)g,
      (__attribute__((address_space(3))) void*)l, 16, 0, 0);
}
// hw trig on fp32 theta (radians) via fp64 range reduction to revolutions
__device__ __forceinline__ void fast_sincos(float theta, float& sn, float& cs) {
  double rev = (double)theta * 0.15915494309189535;  // theta / 2pi
  float fr = (float)(rev - floor(rev));
  sn = __builtin_amdgcn_sinf(fr);
  cs = __builtin_amdgcn_cosf(fr);
}
__device__ __forceinline__ void cvt8(const float* src, short* dst, int i) {
  float4 a = *(const float4*)&src[i];
  float4 b = *(const float4*)&src[i + 4];
  short8 h;
  h[0] = bf16_rne(a.x); h[1] = bf16_rne(a.y);
  h[2] = bf16_rne(a.z); h[3] = bf16_rne(a.w);
  h[4] = bf16_rne(b.x); h[5] = bf16_rne(b.y);
  h[6] = bf16_rne(b.z); h[7] = bf16_rne(b.w);
  *(short8*)&dst[i] = h;
}

// ---------------------------------------------------------------------------
// Fused fp32->bf16 conversion of x, W_q, W_kv, W_out in ONE launch.
// Block 0 additionally computes the 32 RoPE frequencies.
// ---------------------------------------------------------------------------
#define NM (2048 * 2048)
#define NKV (1024 * 2048)

__global__ __launch_bounds__(256) void cvt_all(
    const float* __restrict__ x,    short* __restrict__ xh,
    const float* __restrict__ wq,   short* __restrict__ wqh,
    const float* __restrict__ wkv,  short* __restrict__ wkvh,
    const float* __restrict__ wo,   short* __restrict__ woh,
    float* __restrict__ freqTab) {
  if (blockIdx.x == 0 && threadIdx.x < 32) {
    const double e = (2.0 * threadIdx.x) / 64.0;
    freqTab[threadIdx.x] = (float)pow(10000.0, -e);
  }
  int i = (blockIdx.x * 256 + threadIdx.x) * 8;
  if (i < NM) { cvt8(x, xh, i); return; }
  i -= NM;
  if (i < NM) { cvt8(wq, wqh, i); return; }
  i -= NM;
  if (i < NKV) { cvt8(wkv, wkvh, i); return; }
  i -= NKV;
  cvt8(wo, woh, i);
}

// ---------------------------------------------------------------------------
// QKV projection GEMM with FUSED RoPE + pack epilogue. BM=128 BN=64.
// 1D grid 768, XCD-aware decode: region r = b&7 pinned to XCD r (dispatch
// round-robins blocks over the 8 XCDs), regions are 12x by 8y so each XCD's
// co-resident set is B 12x256KB=3MB + A 8x512KB=4MB (vs ~16MB random ->
// L2 thrash -> everything from L3). Math bit-identical to R12.
// ---------------------------------------------------------------------------
#define QSCALE 0.18033688011112042f   // (1/8) * log2(e)

__global__ __launch_bounds__(256) void gemm_qkv_rope(
    const short* __restrict__ Ah,
    const short* __restrict__ Bq, const short* __restrict__ Bkv,
    const float* __restrict__ bq, const float* __restrict__ bkv,
    const float* __restrict__ tab,
    short* __restrict__ Qrm, short* __restrict__ Krm,
    short* __restrict__ Vt) {
  const int Nq = 2048, K = 2048;
  __shared__ short As[2][128 * 32];
  __shared__ short Bs[2][64 * 32];
  const int tid = threadIdx.x;
  const int w = tid >> 6, lane = tid & 63;
  const int l16 = lane & 15, quad = lane >> 4;

  // XCD-aware 2D decode: 8 regions of 12x x 8y
  const int b = blockIdx.x;
  const int r = b & 7, ri = b >> 3;          // region = XCD, index in region
  const int bx = (r & 3) * 12 + ri % 12;     // 0..47
  const int by = (r >> 2) * 8 + ri / 12;     // 0..15
  const int bm = by * 128;
  const int bnG = bx * 64;

  const short* Bsrc; const float* bias; int bn;
  if (bnG < Nq) { Bsrc = Bq;  bias = bq;  bn = bnG; }
  else          { Bsrc = Bkv; bias = bkv; bn = bnG - Nq; }
  const int mode = (bnG < Nq) ? 0 : ((bnG < Nq + 512) ? 1 : 2);

  const int drow0 = w * 16 + (lane >> 2);
  const int drow1 = drow0 + 64;
  const int slot = lane & 3;
  const int ch0 = slot ^ ((drow0 >> 1) & 3);
  const int ch1 = slot ^ ((drow1 >> 1) & 3);
  const size_t a0 = (size_t)(bm + drow0) * K + ch0 * 8;
  const size_t a1 = (size_t)(bm + drow1) * K + ch1 * 8;
  const size_t b0 = (size_t)(bn + drow0) * K + ch0 * 8;
  const int dA0 = (w * 16) * 32, dA1 = (64 + w * 16) * 32;

  const int wm = (w & 1) * 64, wn = (w >> 1) * 32;
  int offA[4], offB[2];
#pragma unroll
  for (int i = 0; i < 4; ++i) {
    int R = wm + i * 16 + l16;
    offA[i] = R * 32 + (quad ^ ((R >> 1) & 3)) * 8;
  }
#pragma unroll
  for (int j = 0; j < 2; ++j) {
    int R = wn + j * 16 + l16;
    offB[j] = R * 32 + (quad ^ ((R >> 1) & 3)) * 8;
  }

  f32x4 acc[4][2];
#pragma unroll
  for (int i = 0; i < 4; ++i)
#pragma unroll
    for (int j = 0; j < 2; ++j)
#pragma unroll
      for (int e = 0; e < 4; ++e) acc[i][j][e] = 0.f;

  const int T = K / 32;
  dma16(Ah + a0, &As[0][dA0]);
  dma16(Ah + a1, &As[0][dA1]);
  dma16(Bsrc + b0, &Bs[0][dA0]);
  __syncthreads();

  for (int t = 0; t < T; ++t) {
    const int cur = t & 1, nxt = cur ^ 1;
    if (t + 1 < T) {
      const int ko = (t + 1) * 32;
      dma16(Ah + a0 + ko, &As[nxt][dA0]);
      dma16(Ah + a1 + ko, &As[nxt][dA1]);
      dma16(Bsrc + b0 + ko, &Bs[nxt][dA0]);
    }
    short8 af[4], bf[2];
#pragma unroll
    for (int i = 0; i < 4; ++i) af[i] = *(const short8*)&As[cur][offA[i]];
#pragma unroll
    for (int j = 0; j < 2; ++j) bf[j] = *(const short8*)&Bs[cur][offB[j]];
#pragma unroll
    for (int i = 0; i < 4; ++i)
#pragma unroll
      for (int j = 0; j < 2; ++j)
        acc[i][j] = __builtin_amdgcn_mfma_f32_16x16x32_bf16(af[i], bf[j], acc[i][j], 0, 0, 0);
    __syncthreads();
  }

  // ---- fused epilogue (RoPE via lane^1 exchange; V transpose free) ----
#pragma unroll
  for (int i = 0; i < 4; ++i) {
    const int row0 = bm + wm + i * 16 + quad * 4;
#pragma unroll
    for (int j = 0; j < 2; ++j) {
      const int col = bn + wn + j * 16 + l16;
      const float bv = bias[col];
      if (mode == 2) {
        const int d = col - 512;
        short4 sv;
        sv.x = bf16_rne(acc[i][j][0] + bv);
        sv.y = bf16_rne(acc[i][j][1] + bv);
        sv.z = bf16_rne(acc[i][j][2] + bv);
        sv.w = bf16_rne(acc[i][j][3] + bv);
        *(short4*)&Vt[(size_t)d * S_LEN + row0] = sv;
      } else {
        const float fr = tab[(col & 63) >> 1];
        const float sgn = (col & 1) ? 1.f : -1.f;
#pragma unroll
        for (int e = 0; e < 4; ++e) {
          float v = acc[i][j][e] + bv;
          float other = __shfl_xor(v, 1);
          float sn, cs;
          fast_sincos((float)(row0 + e) * fr, sn, cs);
          const float o = v * cs + sgn * other * sn;
          if (mode == 0)
            Qrm[(size_t)(row0 + e) * D_MODEL + col] = bf16_rne(o * QSCALE);
          else
            Krm[(size_t)(row0 + e) * 512 + col] = bf16_rne(o);
        }
      }
    }
  }
}

// ---------------------------------------------------------------------------
// Single-output bf16 NT GEMM, BM=BN=128 (out-projection). 1D grid 256,
// XCD-aware decode: 8 regions of 8x x 4y -> per-XCD set B 4MB + A 2MB.
// ---------------------------------------------------------------------------
__global__ __launch_bounds__(256) void gemm_nt1_big(
    const short* __restrict__ A, const short* __restrict__ B,
    const float* __restrict__ bias, float* __restrict__ C,
    int N, int K) {
  __shared__ short As[2][128 * 32];
  __shared__ short Bs[2][128 * 32];
  const int tid = threadIdx.x;
  const int w = tid >> 6, lane = tid & 63;
  const int l16 = lane & 15, quad = lane >> 4;

  const int b = blockIdx.x;
  const int r = b & 7, ri = b >> 3;          // region = XCD
  const int bx = (r & 1) * 8 + ri % 8;       // 0..15
  const int by = (r >> 1) * 4 + ri / 8;      // 0..15
  const int bm = by * 128;
  const int bn = bx * 128;

  const int drow0 = w * 16 + (lane >> 2);
  const int drow1 = drow0 + 64;
  const int slot = lane & 3;
  const int ch0 = slot ^ ((drow0 >> 1) & 3);
  const int ch1 = slot ^ ((drow1 >> 1) & 3);
  const short* gA0 = &A[(size_t)(bm + drow0) * K + ch0 * 8];
  const short* gA1 = &A[(size_t)(bm + drow1) * K + ch1 * 8];
  const short* gB0 = &B[(size_t)(bn + drow0) * K + ch0 * 8];
  const short* gB1 = &B[(size_t)(bn + drow1) * K + ch1 * 8];
  const int dA0 = (w * 16) * 32, dA1 = (64 + w * 16) * 32;

  const int wm = (w & 1) * 64, wn = (w >> 1) * 64;
  int offA[4], offB[4];
#pragma unroll
  for (int i = 0; i < 4; ++i) {
    int R = wm + i * 16 + l16;
    offA[i] = R * 32 + (quad ^ ((R >> 1) & 3)) * 8;
    int Rb = wn + i * 16 + l16;
    offB[i] = Rb * 32 + (quad ^ ((Rb >> 1) & 3)) * 8;
  }

  f32x4 acc[4][4];
#pragma unroll
  for (int i = 0; i < 4; ++i)
#pragma unroll
    for (int j = 0; j < 4; ++j)
#pragma unroll
      for (int e = 0; e < 4; ++e) acc[i][j][e] = 0.f;

  const int T = K / 32;
  dma16(gA0, &As[0][dA0]);
  dma16(gA1, &As[0][dA1]);
  dma16(gB0, &Bs[0][dA0]);
  dma16(gB1, &Bs[0][dA1]);
  __syncthreads();

  for (int t = 0; t < T; ++t) {
    const int cur = t & 1, nxt = cur ^ 1;
    if (t + 1 < T) {
      const int ko = (t + 1) * 32;
      dma16(gA0 + ko, &As[nxt][dA0]);
      dma16(gA1 + ko, &As[nxt][dA1]);
      dma16(gB0 + ko, &Bs[nxt][dA0]);
      dma16(gB1 + ko, &Bs[nxt][dA1]);
    }
    short8 af[4], bf[4];
#pragma unroll
    for (int i = 0; i < 4; ++i) af[i] = *(const short8*)&As[cur][offA[i]];
#pragma unroll
    for (int j = 0; j < 4; ++j) bf[j] = *(const short8*)&Bs[cur][offB[j]];
#pragma unroll
    for (int i = 0; i < 4; ++i)
#pragma unroll
      for (int j = 0; j < 4; ++j)
        acc[i][j] = __builtin_amdgcn_mfma_f32_16x16x32_bf16(af[i], bf[j], acc[i][j], 0, 0, 0);
    __syncthreads();
  }

#pragma unroll
  for (int i = 0; i < 4; ++i) {
#pragma unroll
    for (int j = 0; j < 4; ++j) {
      const int col = bn + wn + j * 16 + l16;
      const float bv = bias[col];
      const int row0 = bm + wm + i * 16 + quad * 4;
#pragma unroll
      for (int e = 0; e < 4; ++e)
        C[(size_t)(row0 + e) * N + col] = acc[i][j][e] + bv;
    }
  }
}

// ---------------------------------------------------------------------------
// MFMA flash attention v8 (unchanged from R12).
// ---------------------------------------------------------------------------
__global__ __launch_bounds__(256, 4) void flash8(
    const short* __restrict__ Qrm, const short* __restrict__ Krm,
    const short* __restrict__ Vt, short* __restrict__ Oh) {
  const int qt = blockIdx.x, h = blockIdx.y;
  const int kvh = h >> 2;
  const int tid = threadIdx.x;
  const int w = tid >> 6, lane = tid & 63;
  const int l16 = lane & 15, quad = lane >> 4;

  __shared__ short Ks[2][64 * 64];
  __shared__ short Vs[2][64 * 64];
  __shared__ short Ps[64 * 64];

  const short* Vh = Vt + (size_t)kvh * 64 * S_LEN;
  const int qr = qt * 64 + w * 16 + l16;

  short8 qf0 = *(const short8*)&Qrm[(size_t)qr * D_MODEL + h * 64 + quad * 8];
  short8 qf1 = *(const short8*)&Qrm[(size_t)qr * D_MODEL + h * 64 + 32 + quad * 8];

  short8 ones;
#pragma unroll
  for (int e = 0; e < 8; ++e) ones[e] = (short)0x3F80;   // bf16 1.0

  const int drow = lane >> 3;
  const int ch = (lane & 7) ^ drow;
  const short* gK = &Krm[(size_t)(w * 16 + drow) * 512 + kvh * 64 + ch * 8];
  const short* gV = &Vh[(size_t)(w * 16 + drow) * S_LEN + ch * 8];

  const int sl0 = quad ^ (l16 & 7);
  int offT[4][2];
#pragma unroll
  for (int m = 0; m < 4; ++m) {
    offT[m][0] = (m * 16 + l16) * 64 + sl0 * 8;
    offT[m][1] = (m * 16 + l16) * 64 + (sl0 ^ 4) * 8;
  }

  const int prow = (w * 16 + l16) * 64;
  const int pswz = (l16 & 7) << 1;
  int pwr[4];
#pragma unroll
  for (int m = 0; m < 4; ++m) pwr[m] = prow + ((4 * m + quad) ^ pswz) * 4;
  const int prd0 = prow + ((2 * quad) ^ pswz) * 4;
  const int prd1 = prow + ((8 + 2 * quad) ^ pswz) * 4;

  f32x4 accl;
#pragma unroll
  for (int e = 0; e < 4; ++e) accl[e] = 0.f;
  f32x4 acco[4];
#pragma unroll
  for (int m = 0; m < 4; ++m)
#pragma unroll
    for (int e = 0; e < 4; ++e) acco[m][e] = 0.f;

  dma16(gK,               &Ks[0][(w * 16) * 64]);
  dma16(gK + 8 * 512,     &Ks[0][(w * 16 + 8) * 64]);
  dma16(gV,               &Vs[0][(w * 16) * 64]);
  dma16(gV + 8 * S_LEN,   &Vs[0][(w * 16 + 8) * 64]);
  __syncthreads();

  for (int t = 0; t < 32; ++t) {
    const int cur = t & 1, nxt = cur ^ 1;
    if (t + 1 < 32) {
      const short* gKn = gK + (size_t)(t + 1) * 64 * 512;
      const short* gVn = gV + (t + 1) * 64;
      dma16(gKn,             &Ks[nxt][(w * 16) * 64]);
      dma16(gKn + 8 * 512,   &Ks[nxt][(w * 16 + 8) * 64]);
      dma16(gVn,             &Vs[nxt][(w * 16) * 64]);
      dma16(gVn + 8 * S_LEN, &Vs[nxt][(w * 16 + 8) * 64]);
    }

    const short* kc = Ks[cur];
    f32x4 accs[4];
#pragma unroll
    for (int m = 0; m < 4; ++m)
#pragma unroll
      for (int e = 0; e < 4; ++e) accs[m][e] = 0.f;
#pragma unroll
    for (int m = 0; m < 4; ++m) {
      short8 k0 = *(const short8*)&kc[offT[m][0]];
      short8 k1 = *(const short8*)&kc[offT[m][1]];
      accs[m] = __builtin_amdgcn_mfma_f32_16x16x32_bf16(k0, qf0, accs[m], 0, 0, 0);
      accs[m] = __builtin_amdgcn_mfma_f32_16x16x32_bf16(k1, qf1, accs[m], 0, 0, 0);
    }

#pragma unroll
    for (int m = 0; m < 4; ++m) {
      float p0 = exp2f(accs[m][0]);
      float p1 = exp2f(accs[m][1]);
      float p2 = exp2f(accs[m][2]);
      float p3 = exp2f(accs[m][3]);
      unsigned u01 = __builtin_amdgcn_perm(__float_as_uint(p1), __float_as_uint(p0), 0x07060302u);
      unsigned u23 = __builtin_amdgcn_perm(__float_as_uint(p3), __float_as_uint(p2), 0x07060302u);
      *(uint2*)&Ps[pwr[m]] = make_uint2(u01, u23);
    }

    short8 pf0 = *(const short8*)&Ps[prd0];
    short8 pf1 = *(const short8*)&Ps[prd1];
    accl = __builtin_amdgcn_mfma_f32_16x16x32_bf16(ones, pf0, accl, 0, 0, 0);
    accl = __builtin_amdgcn_mfma_f32_16x16x32_bf16(ones, pf1, accl, 0, 0, 0);
    const short* vc = Vs[cur];
#pragma unroll
    for (int m = 0; m < 4; ++m) {
      short8 v0 = *(const short8*)&vc[offT[m][0]];
      short8 v1 = *(const short8*)&vc[offT[m][1]];
      acco[m] = __builtin_amdgcn_mfma_f32_16x16x32_bf16(v0, pf0, acco[m], 0, 0, 0);
      acco[m] = __builtin_amdgcn_mfma_f32_16x16x32_bf16(v1, pf1, acco[m], 0, 0, 0);
    }

    __syncthreads();
  }

  const float inv = 1.f / accl[0];
#pragma unroll
  for (int m = 0; m < 4; ++m) {
    short4 h4;
    h4.x = bf16_rne(acco[m][0] * inv);
    h4.y = bf16_rne(acco[m][1] * inv);
    h4.z = bf16_rne(acco[m][2] * inv);
    h4.w = bf16_rne(acco[m][3] * inv);
    const size_t base = (size_t)qr * D_MODEL + h * 64 + m * 16 + quad * 4;
    *(short4*)&Oh[base] = h4;
  }
}

// ---------------------------------------------------------------------------
extern "C" void kernel_launch(void* const* d_in, const int* in_sizes, int n_in,
                              void* d_out, int out_size, void* d_ws, size_t ws_size,
                              hipStream_t stream) {
  const float* x     = (const float*)d_in[0];
  const float* W_q   = (const float*)d_in[1];
  const float* b_q   = (const float*)d_in[2];
  const float* W_kv  = (const float*)d_in[3];
  const float* b_kv  = (const float*)d_in[4];
  const float* W_out = (const float*)d_in[5];
  const float* b_out = (const float*)d_in[6];
  float* out = (float*)d_out;

  char* ws = (char*)d_ws;                        // ~41 MB used
  short* xh    = (short*)(ws);                   //  8 MB
  short* Wqh   = (short*)(ws + (8u << 20));      //  8 MB
  short* Wkvh  = (short*)(ws + (16u << 20));     //  4 MB
  short* Woh   = (short*)(ws + (20u << 20));     //  8 MB
  short* Qrm   = (short*)(ws + (28u << 20));     //  8 MB bf16 [2048][2048]
  short* Krm   = (short*)(ws + (36u << 20));     //  2 MB bf16 [2048][512]
  short* Vtb   = (short*)(ws + (38u << 20));     //  2 MB bf16 [8][64][2048]
  float* freqTab = (float*)(ws + (40u << 20));   //  128 B
  short* Ath   = xh;   // x dead after gemm_qkv_rope

  // fused conversion + freq-table launch
  cvt_all<<<7168, 256, 0, stream>>>(x, xh, W_q, Wqh, W_kv, Wkvh, W_out, Woh,
                                    freqTab);

  // QKV projection, XCD-swizzled 1D grid (768 blocks)
  gemm_qkv_rope<<<768, 256, 0, stream>>>(
      xh, Wqh, Wkvh, b_q, b_kv, freqTab, Qrm, Krm, Vtb);

  flash8<<<dim3(S_LEN / 64, Q_HEADS), 256, 0, stream>>>(Qrm, Krm, Vtb, Ath);

  // out-projection, XCD-swizzled 1D grid (256 blocks)
  gemm_nt1_big<<<256, 256, 0, stream>>>(Ath, Woh, b_out, out, 2048, 2048);
}